// Round 1
// baseline (273.333 us; speedup 1.0000x reference)
//
#include <hip/hip_runtime.h>
#include <math.h>

#define S      4096
#define BEV    16
#define KNN    5
#define NTH    256
#define RPB    64          // query rows per block
#define BIGF   1.0e9f
#define SENT   4.0e9f      // sentinel xx for non-candidate points (>> BIGF)

__device__ __forceinline__ float fmulrn(float a, float b) { return __fmul_rn(a, b); }
__device__ __forceinline__ float faddrn(float a, float b) { return __fadd_rn(a, b); }

// ---------------- kernel 1: per-event max score -> mrss[b] ----------------
__global__ __launch_bounds__(NTH) void k_event_max(const float* __restrict__ score,
                                                   float* __restrict__ mrss) {
    int b = blockIdx.x;
    const float* s = score + (size_t)b * S;
    float m = -3.0e38f;
    for (int t = threadIdx.x; t < S; t += NTH) m = fmaxf(m, s[t]);
#pragma unroll
    for (int off = 32; off >= 1; off >>= 1) m = fmaxf(m, __shfl_xor(m, off, 64));
    __shared__ float red[NTH / 64];
    if ((threadIdx.x & 63) == 0) red[threadIdx.x >> 6] = m;
    __syncthreads();
    if (threadIdx.x == 0) {
        float mm = red[0];
        for (int w = 1; w < NTH / 64; w++) mm = fmaxf(mm, red[w]);
        mrss[b] = mm;
    }
}

// ---------------- kernel 2: thr_eff = min(min(mrss)*0.98, 0.5) ----------------
__global__ void k_thr(const float* __restrict__ mrss, float* __restrict__ thr) {
    float m = mrss[0];
    for (int b = 1; b < BEV; b++) m = fminf(m, mrss[b]);
    thr[0] = fminf(__fmul_rn(m, 0.98f), 0.5f);
}

// ---- kernel 3: sel_mask + counts + query compaction + defaults for non-query rows ----
__global__ __launch_bounds__(NTH) void k_sel(const float* __restrict__ score,
                                             const float* __restrict__ thrp,
                                             int* __restrict__ counts,
                                             int* __restrict__ qcount,
                                             int* __restrict__ qlist,
                                             float* __restrict__ out_nidx,
                                             float* __restrict__ out_dist,
                                             float* __restrict__ out_w,
                                             float* __restrict__ out_sel) {
    int b = blockIdx.x;
    float thr = thrp[0];
    int cnt = 0;
    for (int p = threadIdx.x; p < S; p += NTH) {
        size_t gi = (size_t)b * S + p;
        float sc = score[gi];
        bool sel = (sc >= thr);
        cnt += sel ? 1 : 0;
        out_sel[gi] = sel ? 1.0f : 0.0f;
        if (sc > 0.5f) {
            // direction 0: not a query row -> reference outputs fixed defaults
#pragma unroll
            for (int k = 0; k < KNN; k++) {
                out_nidx[gi * KNN + k] = -1.0f;
                out_dist[gi * KNN + k] = 0.0f;
                out_w[gi * KNN + k]    = 0.2f;   // softmax of 5 equal values
            }
        } else {
            int pos = atomicAdd(&qcount[b], 1);
            qlist[(size_t)b * S + pos] = p;
        }
    }
#pragma unroll
    for (int off = 32; off >= 1; off >>= 1) cnt += __shfl_xor(cnt, off, 64);
    __shared__ int red[NTH / 64];
    if ((threadIdx.x & 63) == 0) red[threadIdx.x >> 6] = cnt;
    __syncthreads();
    if (threadIdx.x == 0) {
        int c = 0;
        for (int w = 0; w < NTH / 64; w++) c += red[w];
        counts[b] = c;
    }
}

// ---------------- kernel 4: rs_up prefix sum (17 floats) ----------------
__global__ void k_rsup(const int* __restrict__ counts, float* __restrict__ rs_up) {
    int acc = 0;
    rs_up[0] = 0.0f;
    for (int b = 0; b < BEV; b++) { acc += counts[b]; rs_up[b + 1] = (float)acc; }
}

// ---------------- kernel 5: directional KNN for query rows ----------------
__global__ __launch_bounds__(NTH) void k_knn(const float* __restrict__ coords,
                                             const float* __restrict__ score,
                                             const int* __restrict__ qcount,
                                             const int* __restrict__ qlist,
                                             float* __restrict__ out_nidx,
                                             float* __restrict__ out_dist,
                                             float* __restrict__ out_w) {
    __shared__ float4 pts[S];   // 64 KB: (-2x, -2y, -2z, xx or SENT)
    int b   = blockIdx.x >> 6;
    int blk = blockIdx.x & 63;
    int qc  = qcount[b];
    if (blk * RPB >= qc) return;     // uniform per block

    for (int p = threadIdx.x; p < S; p += NTH) {
        const float* c = coords + ((size_t)b * S + p) * 3;
        float x = c[0], y = c[1], z = c[2];
        float xx = faddrn(faddrn(fmulrn(x, x), fmulrn(y, y)), fmulrn(z, z));
        float sc = score[(size_t)b * S + p];
        float wv = (sc > 0.5f) ? xx : SENT;  // candidate iff direction==0
        pts[p] = make_float4(fmulrn(-2.0f, x), fmulrn(-2.0f, y), fmulrn(-2.0f, z), wv);
    }
    __syncthreads();

    int row_slot = threadIdx.x >> 2;
    int part     = threadIdx.x & 3;
    int r        = blk * RPB + row_slot;
    bool active  = (r < qc);
    int irow     = active ? qlist[(size_t)b * S + r] : 0;

    const float* ci = coords + ((size_t)b * S + irow) * 3;
    float xi = ci[0], yi = ci[1], zi = ci[2];
    float xxi = faddrn(faddrn(fmulrn(xi, xi), fmulrn(yi, yi)), fmulrn(zi, zi));

    // sorted ascending top-5 (d, idx); strict-< insert => lower index wins ties
    float d0 = 3.0e38f, d1 = 3.0e38f, d2v = 3.0e38f, d3 = 3.0e38f, d4 = 3.0e38f;
    int   i0 = -1, i1 = -1, i2 = -1, i3 = -1, i4 = -1;

#pragma unroll 4
    for (int j = part; j < S; j += 4) {
        float4 p = pts[j];
        // dm = -2*dot (exact: scaling by -2 commutes with rounding)
        float dm = faddrn(faddrn(fmulrn(p.x, xi), fmulrn(p.y, yi)), fmulrn(p.z, zi));
        float dd = faddrn(faddrn(xxi, p.w), dm);   // (xxi+xxj) - 2*dot, same rounding as ref
        dd = fmaxf(dd, 0.0f);
        if (dd < d4) {
            d4 = dd; i4 = j;
            if (d4 < d3) { float t = d3; d3 = d4; d4 = t; int u = i3; i3 = i4; i4 = u; }
            if (d3 < d2v){ float t = d2v; d2v = d3; d3 = t; int u = i2; i2 = i3; i3 = u; }
            if (d2v < d1){ float t = d1; d1 = d2v; d2v = t; int u = i1; i1 = i2; i2 = u; }
            if (d1 < d0) { float t = d0; d0 = d1; d1 = t; int u = i0; i0 = i1; i1 = u; }
        }
    }

    float av[KNN] = { d0, d1, d2v, d3, d4 };
    int   ai[KNN] = { i0, i1, i2, i3, i4 };

    // merge the 4 partial sorted lists across lanes (part 0..3) lexicographically by (d, idx)
#pragma unroll
    for (int off = 1; off <= 2; off <<= 1) {
        float bv[KNN]; int bi[KNN];
#pragma unroll
        for (int k = 0; k < KNN; k++) {
            bv[k] = __shfl_xor(av[k], off, 64);
            bi[k] = __shfl_xor(ai[k], off, 64);
        }
        float mv[KNN]; int mi[KNN];
#pragma unroll
        for (int k = 0; k < KNN; k++) {
            float bestv = 3.3e38f; int besti = 0x7fffffff;
#pragma unroll
            for (int t = 0; t <= k + 1; t++) {   // t elements from A, k+1-t from B
                float x1 = (t > 0)         ? av[t - 1] : -3.3e38f;
                int   y1 = (t > 0)         ? ai[t - 1] : -2;
                float x2 = (k - t >= 0)    ? bv[k - t] : -3.3e38f;
                int   y2 = (k - t >= 0)    ? bi[k - t] : -2;
                bool a_gt = (x1 > x2) || (x1 == x2 && y1 > y2);
                float cv = a_gt ? x1 : x2;
                int   ci2 = a_gt ? y1 : y2;
                bool c_lt = (cv < bestv) || (cv == bestv && ci2 < besti);
                bestv = c_lt ? cv : bestv;
                besti = c_lt ? ci2 : besti;
            }
            mv[k] = bestv; mi[k] = besti;
        }
#pragma unroll
        for (int k = 0; k < KNN; k++) { av[k] = mv[k]; ai[k] = mi[k]; }
    }

    if (part == 0 && active) {
        size_t gi = (size_t)b * S + irow;
        float dk[KNN], nk[KNN], e[KNN];
        float m = -3.0e38f;
#pragma unroll
        for (int k = 0; k < KNN; k++) {
            bool val = (av[k] < BIGF);
            dk[k] = val ? av[k] : 0.0f;
            nk[k] = val ? (float)(b * S + ai[k]) : -1.0f;
            e[k]  = expf(-dk[k]);
            m = fmaxf(m, e[k]);
        }
        float u[KNN], ssum = 0.0f;
#pragma unroll
        for (int k = 0; k < KNN; k++) { u[k] = expf(e[k] - m); ssum += u[k]; }
#pragma unroll
        for (int k = 0; k < KNN; k++) {
            out_nidx[gi * KNN + k] = nk[k];
            out_dist[gi * KNN + k] = dk[k];
            out_w[gi * KNN + k]    = u[k] / ssum;
        }
    }
}

extern "C" void kernel_launch(void* const* d_in, const int* in_sizes, int n_in,
                              void* d_out, int out_size, void* d_ws, size_t ws_size,
                              hipStream_t stream) {
    const float* score  = (const float*)d_in[0];
    const float* coords = (const float*)d_in[1];
    // d_in[2] (rs) not needed: uniform splits by construction

    float* out = (float*)d_out;
    size_t NK = (size_t)BEV * S * KNN;
    float* out_nidx = out;
    float* out_dist = out + NK;
    float* out_w    = out + 2 * NK;
    float* out_rsup = out + 3 * NK;
    float* out_sel  = out + 3 * NK + (BEV + 1);

    char* ws     = (char*)d_ws;
    float* mrss  = (float*)(ws);          // 16 floats
    float* thr   = (float*)(ws + 64);     // 1 float
    int*   counts= (int*)(ws + 128);      // 16 ints
    int*   qcount= (int*)(ws + 192);      // 16 ints
    int*   qlist = (int*)(ws + 256);      // BEV*S ints

    hipMemsetAsync(qcount, 0, 64, stream);
    k_event_max<<<BEV, NTH, 0, stream>>>(score, mrss);
    k_thr<<<1, 1, 0, stream>>>(mrss, thr);
    k_sel<<<BEV, NTH, 0, stream>>>(score, thr, counts, qcount, qlist,
                                   out_nidx, out_dist, out_w, out_sel);
    k_rsup<<<1, 1, 0, stream>>>(counts, out_rsup);
    k_knn<<<BEV * (S / RPB), NTH, 0, stream>>>(coords, score, qcount, qlist,
                                               out_nidx, out_dist, out_w);
}

// Round 2
// 206.739 us; speedup vs baseline: 1.3221x; 1.3221x over previous
//
#include <hip/hip_runtime.h>
#include <math.h>

#define S      4096
#define BEV    16
#define KNN    5
#define NTH    256
#define RPB    64          // rows per block (fallback kernel)
#define BIGF   1.0e9f
#define SENT   4.0e9f      // sentinel xx for non-candidate points (>> BIGF)

__device__ __forceinline__ float fmulrn(float a, float b) { return __fmul_rn(a, b); }
__device__ __forceinline__ float faddrn(float a, float b) { return __fadd_rn(a, b); }

// ---------------- kernel 1: per-event max score -> mrss[b] ----------------
__global__ __launch_bounds__(NTH) void k_event_max(const float* __restrict__ score,
                                                   float* __restrict__ mrss) {
    int b = blockIdx.x;
    const float* s = score + (size_t)b * S;
    float m = -3.0e38f;
    for (int t = threadIdx.x; t < S; t += NTH) m = fmaxf(m, s[t]);
#pragma unroll
    for (int off = 32; off >= 1; off >>= 1) m = fmaxf(m, __shfl_xor(m, off, 64));
    __shared__ float red[NTH / 64];
    if ((threadIdx.x & 63) == 0) red[threadIdx.x >> 6] = m;
    __syncthreads();
    if (threadIdx.x == 0) {
        float mm = red[0];
        for (int w = 1; w < NTH / 64; w++) mm = fmaxf(mm, red[w]);
        mrss[b] = mm;
    }
}

// ---------------- kernel 2: thr_eff = min(min(mrss)*0.98, 0.5) ----------------
__global__ void k_thr(const float* __restrict__ mrss, float* __restrict__ thr) {
    float m = mrss[0];
    for (int b = 1; b < BEV; b++) m = fminf(m, mrss[b]);
    thr[0] = fminf(__fmul_rn(m, 0.98f), 0.5f);
}

// ---- kernel 3: sel_mask + counts + query compaction + pts prep + defaults ----
__global__ __launch_bounds__(NTH) void k_sel(const float* __restrict__ score,
                                             const float* __restrict__ coords,
                                             const float* __restrict__ thrp,
                                             int* __restrict__ counts,
                                             int* __restrict__ qcount,
                                             int* __restrict__ qlist,
                                             float4* __restrict__ pts,   // may be null
                                             float* __restrict__ out_nidx,
                                             float* __restrict__ out_dist,
                                             float* __restrict__ out_w,
                                             float* __restrict__ out_sel) {
    int b = blockIdx.x;
    float thr = thrp[0];
    int cnt = 0;
    for (int p = threadIdx.x; p < S; p += NTH) {
        size_t gi = (size_t)b * S + p;
        float sc = score[gi];
        bool sel = (sc >= thr);
        cnt += sel ? 1 : 0;
        out_sel[gi] = sel ? 1.0f : 0.0f;
        if (pts) {
            const float* c = coords + gi * 3;
            float x = c[0], y = c[1], z = c[2];
            float xx = faddrn(faddrn(fmulrn(x, x), fmulrn(y, y)), fmulrn(z, z));
            pts[gi] = make_float4(fmulrn(-2.0f, x), fmulrn(-2.0f, y), fmulrn(-2.0f, z),
                                  (sc > 0.5f) ? xx : SENT);
        }
        if (sc > 0.5f) {
            // direction 0: not a query row -> reference outputs fixed defaults
#pragma unroll
            for (int k = 0; k < KNN; k++) {
                out_nidx[gi * KNN + k] = -1.0f;
                out_dist[gi * KNN + k] = 0.0f;
                out_w[gi * KNN + k]    = 0.2f;   // softmax of 5 equal values
            }
        } else {
            int pos = atomicAdd(&qcount[b], 1);
            qlist[(size_t)b * S + pos] = p;
        }
    }
#pragma unroll
    for (int off = 32; off >= 1; off >>= 1) cnt += __shfl_xor(cnt, off, 64);
    __shared__ int red[NTH / 64];
    if ((threadIdx.x & 63) == 0) red[threadIdx.x >> 6] = cnt;
    __syncthreads();
    if (threadIdx.x == 0) {
        int c = 0;
        for (int w = 0; w < NTH / 64; w++) c += red[w];
        counts[b] = c;
    }
}

// ---------------- kernel 4: rs_up prefix sum (17 floats) ----------------
__global__ void k_rsup(const int* __restrict__ counts, float* __restrict__ rs_up) {
    int acc = 0;
    rs_up[0] = 0.0f;
    for (int b = 0; b < BEV; b++) { acc += counts[b]; rs_up[b + 1] = (float)acc; }
}

// -------- kernel 5: sliced KNN, one query row per thread, partial top-5 --------
__global__ __launch_bounds__(NTH) void k_knn_part(const float* __restrict__ coords,
                                                  const int* __restrict__ qcount,
                                                  const int* __restrict__ qlist,
                                                  const float4* __restrict__ pts,
                                                  float* __restrict__ pd,
                                                  int* __restrict__ pi,
                                                  int slen, int nslice) {
    int b     = blockIdx.z;
    int slice = blockIdx.y;
    int r     = blockIdx.x * NTH + threadIdx.x;
    int qc    = qcount[b];
    if (r >= qc) return;
    int irow = qlist[(size_t)b * S + r];

    const float* ci = coords + ((size_t)b * S + irow) * 3;
    float xi = ci[0], yi = ci[1], zi = ci[2];
    float xxi = faddrn(faddrn(fmulrn(xi, xi), fmulrn(yi, yi)), fmulrn(zi, zi));

    const float4* __restrict__ pp = pts + (size_t)b * S + (size_t)slice * slen;
    int base = slice * slen;

    float d0 = 3.0e38f, d1 = 3.0e38f, d2v = 3.0e38f, d3 = 3.0e38f, d4 = 3.0e38f;
    int   i0 = -1, i1 = -1, i2 = -1, i3 = -1, i4 = -1;

#pragma unroll 4
    for (int j = 0; j < slen; j++) {
        float4 p = pp[j];                 // wave-uniform address -> broadcast load
        float dm = faddrn(faddrn(fmulrn(p.x, xi), fmulrn(p.y, yi)), fmulrn(p.z, zi));
        float dd = faddrn(faddrn(xxi, p.w), dm);  // (xxi+xxj) - 2*dot, ref rounding
        dd = fmaxf(dd, 0.0f);
        if (dd < d4) {
            d4 = dd; i4 = base + j;
            if (d4 < d3) { float t = d3; d3 = d4; d4 = t; int u = i3; i3 = i4; i4 = u; }
            if (d3 < d2v){ float t = d2v; d2v = d3; d3 = t; int u = i2; i2 = i3; i3 = u; }
            if (d2v < d1){ float t = d1; d1 = d2v; d2v = t; int u = i1; i1 = i2; i2 = u; }
            if (d1 < d0) { float t = d0; d0 = d1; d1 = t; int u = i0; i0 = i1; i1 = u; }
        }
    }

    size_t po = ((size_t)b * S + r) * (size_t)(nslice * KNN) + (size_t)slice * KNN;
    pd[po + 0] = d0;  pi[po + 0] = i0;
    pd[po + 1] = d1;  pi[po + 1] = i1;
    pd[po + 2] = d2v; pi[po + 2] = i2;
    pd[po + 3] = d3;  pi[po + 3] = i3;
    pd[po + 4] = d4;  pi[po + 4] = i4;
}

// -------- kernel 6: merge slice partials, epilogue (dist/nidx/weights) --------
__global__ __launch_bounds__(NTH) void k_merge(const int* __restrict__ qcount,
                                               const int* __restrict__ qlist,
                                               const float* __restrict__ pd,
                                               const int* __restrict__ pi,
                                               int nslice,
                                               float* __restrict__ out_nidx,
                                               float* __restrict__ out_dist,
                                               float* __restrict__ out_w) {
    int b = blockIdx.y;
    int r = blockIdx.x * NTH + threadIdx.x;
    int qc = qcount[b];
    if (r >= qc) return;
    int irow = qlist[(size_t)b * S + r];

    float a0 = 3.0e38f, a1 = 3.0e38f, a2 = 3.0e38f, a3 = 3.0e38f, a4 = 3.0e38f;
    int   j0 = -1, j1 = -1, j2 = -1, j3 = -1, j4 = -1;

    size_t po = ((size_t)b * S + r) * (size_t)(nslice * KNN);
    for (int s = 0; s < nslice; s++) {
#pragma unroll
        for (int k = 0; k < KNN; k++) {
            float dd = pd[po + (size_t)s * KNN + k];
            int   jj = pi[po + (size_t)s * KNN + k];
            // slices scanned in ascending slice order, lists sorted -> strict-<
            // insertion preserves (d, idx) lexicographic order
            if (dd < a4) {
                a4 = dd; j4 = jj;
                if (a4 < a3) { float t = a3; a3 = a4; a4 = t; int u = j3; j3 = j4; j4 = u; }
                if (a3 < a2) { float t = a2; a2 = a3; a3 = t; int u = j2; j2 = j3; j3 = u; }
                if (a2 < a1) { float t = a1; a1 = a2; a2 = t; int u = j1; j1 = j2; j2 = u; }
                if (a1 < a0) { float t = a0; a0 = a1; a1 = t; int u = j0; j0 = j1; j1 = u; }
            }
        }
    }

    float av[KNN] = { a0, a1, a2, a3, a4 };
    int   ai[KNN] = { j0, j1, j2, j3, j4 };

    size_t gi = (size_t)b * S + irow;
    float dk[KNN], nk[KNN], e[KNN];
    float m = -3.0e38f;
#pragma unroll
    for (int k = 0; k < KNN; k++) {
        bool val = (av[k] < BIGF);
        dk[k] = val ? av[k] : 0.0f;
        nk[k] = val ? (float)(b * S + ai[k]) : -1.0f;
        e[k]  = expf(-dk[k]);
        m = fmaxf(m, e[k]);
    }
    float u[KNN], ssum = 0.0f;
#pragma unroll
    for (int k = 0; k < KNN; k++) { u[k] = expf(e[k] - m); ssum += u[k]; }
#pragma unroll
    for (int k = 0; k < KNN; k++) {
        out_nidx[gi * KNN + k] = nk[k];
        out_dist[gi * KNN + k] = dk[k];
        out_w[gi * KNN + k]    = u[k] / ssum;
    }
}

// ---------------- fallback (round-1) KNN: LDS staging, 4 lanes/row ----------------
__global__ __launch_bounds__(NTH) void k_knn_old(const float* __restrict__ coords,
                                                 const float* __restrict__ score,
                                                 const int* __restrict__ qcount,
                                                 const int* __restrict__ qlist,
                                                 float* __restrict__ out_nidx,
                                                 float* __restrict__ out_dist,
                                                 float* __restrict__ out_w) {
    __shared__ float4 pts[S];
    int b   = blockIdx.x >> 6;
    int blk = blockIdx.x & 63;
    int qc  = qcount[b];
    if (blk * RPB >= qc) return;

    for (int p = threadIdx.x; p < S; p += NTH) {
        const float* c = coords + ((size_t)b * S + p) * 3;
        float x = c[0], y = c[1], z = c[2];
        float xx = faddrn(faddrn(fmulrn(x, x), fmulrn(y, y)), fmulrn(z, z));
        float sc = score[(size_t)b * S + p];
        pts[p] = make_float4(fmulrn(-2.0f, x), fmulrn(-2.0f, y), fmulrn(-2.0f, z),
                             (sc > 0.5f) ? xx : SENT);
    }
    __syncthreads();

    int row_slot = threadIdx.x >> 2;
    int part     = threadIdx.x & 3;
    int r        = blk * RPB + row_slot;
    bool active  = (r < qc);
    int irow     = active ? qlist[(size_t)b * S + r] : 0;

    const float* ci = coords + ((size_t)b * S + irow) * 3;
    float xi = ci[0], yi = ci[1], zi = ci[2];
    float xxi = faddrn(faddrn(fmulrn(xi, xi), fmulrn(yi, yi)), fmulrn(zi, zi));

    float d0 = 3.0e38f, d1 = 3.0e38f, d2v = 3.0e38f, d3 = 3.0e38f, d4 = 3.0e38f;
    int   i0 = -1, i1 = -1, i2 = -1, i3 = -1, i4 = -1;

#pragma unroll 4
    for (int j = part; j < S; j += 4) {
        float4 p = pts[j];
        float dm = faddrn(faddrn(fmulrn(p.x, xi), fmulrn(p.y, yi)), fmulrn(p.z, zi));
        float dd = faddrn(faddrn(xxi, p.w), dm);
        dd = fmaxf(dd, 0.0f);
        if (dd < d4) {
            d4 = dd; i4 = j;
            if (d4 < d3) { float t = d3; d3 = d4; d4 = t; int u = i3; i3 = i4; i4 = u; }
            if (d3 < d2v){ float t = d2v; d2v = d3; d3 = t; int u = i2; i2 = i3; i3 = u; }
            if (d2v < d1){ float t = d1; d1 = d2v; d2v = t; int u = i1; i1 = i2; i2 = u; }
            if (d1 < d0) { float t = d0; d0 = d1; d1 = t; int u = i0; i0 = i1; i1 = u; }
        }
    }

    float av[KNN] = { d0, d1, d2v, d3, d4 };
    int   ai[KNN] = { i0, i1, i2, i3, i4 };

#pragma unroll
    for (int off = 1; off <= 2; off <<= 1) {
        float bv[KNN]; int bi[KNN];
#pragma unroll
        for (int k = 0; k < KNN; k++) {
            bv[k] = __shfl_xor(av[k], off, 64);
            bi[k] = __shfl_xor(ai[k], off, 64);
        }
        float mv[KNN]; int mi[KNN];
#pragma unroll
        for (int k = 0; k < KNN; k++) {
            float bestv = 3.3e38f; int besti = 0x7fffffff;
#pragma unroll
            for (int t = 0; t <= k + 1; t++) {
                float x1 = (t > 0)      ? av[t - 1] : -3.3e38f;
                int   y1 = (t > 0)      ? ai[t - 1] : -2;
                float x2 = (k - t >= 0) ? bv[k - t] : -3.3e38f;
                int   y2 = (k - t >= 0) ? bi[k - t] : -2;
                bool a_gt = (x1 > x2) || (x1 == x2 && y1 > y2);
                float cv = a_gt ? x1 : x2;
                int   ci2 = a_gt ? y1 : y2;
                bool c_lt = (cv < bestv) || (cv == bestv && ci2 < besti);
                bestv = c_lt ? cv : bestv;
                besti = c_lt ? ci2 : besti;
            }
            mv[k] = bestv; mi[k] = besti;
        }
#pragma unroll
        for (int k = 0; k < KNN; k++) { av[k] = mv[k]; ai[k] = mi[k]; }
    }

    if (part == 0 && active) {
        size_t gi = (size_t)b * S + irow;
        float dk[KNN], nk[KNN], e[KNN];
        float m = -3.0e38f;
#pragma unroll
        for (int k = 0; k < KNN; k++) {
            bool val = (av[k] < BIGF);
            dk[k] = val ? av[k] : 0.0f;
            nk[k] = val ? (float)(b * S + ai[k]) : -1.0f;
            e[k]  = expf(-dk[k]);
            m = fmaxf(m, e[k]);
        }
        float u[KNN], ssum = 0.0f;
#pragma unroll
        for (int k = 0; k < KNN; k++) { u[k] = expf(e[k] - m); ssum += u[k]; }
#pragma unroll
        for (int k = 0; k < KNN; k++) {
            out_nidx[gi * KNN + k] = nk[k];
            out_dist[gi * KNN + k] = dk[k];
            out_w[gi * KNN + k]    = u[k] / ssum;
        }
    }
}

extern "C" void kernel_launch(void* const* d_in, const int* in_sizes, int n_in,
                              void* d_out, int out_size, void* d_ws, size_t ws_size,
                              hipStream_t stream) {
    const float* score  = (const float*)d_in[0];
    const float* coords = (const float*)d_in[1];

    float* out = (float*)d_out;
    size_t NK = (size_t)BEV * S * KNN;
    float* out_nidx = out;
    float* out_dist = out + NK;
    float* out_w    = out + 2 * NK;
    float* out_rsup = out + 3 * NK;
    float* out_sel  = out + 3 * NK + (BEV + 1);

    char* ws      = (char*)d_ws;
    float* mrss   = (float*)(ws);          // 16 floats
    float* thr    = (float*)(ws + 64);     // 1 float
    int*   counts = (int*)(ws + 128);      // 16 ints
    int*   qcount = (int*)(ws + 192);      // 16 ints
    int*   qlist  = (int*)(ws + 256);      // BEV*S ints

    size_t off_pts = 256 + (size_t)BEV * S * 4;          // 262400, 16B-aligned
    size_t off_pd  = off_pts + (size_t)BEV * S * 16;     // after 4MB pts

    int nslice = 0;
    {
        const int cands[3] = {4, 2, 1};
        for (int c = 0; c < 3; c++) {
            size_t need = off_pd + 2ull * BEV * S * cands[c] * KNN * 4;
            if (ws_size >= need) { nslice = cands[c]; break; }
        }
    }

    float4* pts = (nslice > 0) ? (float4*)(ws + off_pts) : (float4*)0;
    float*  pd  = (float*)(ws + off_pd);
    int*    pi  = (int*)(pd + (size_t)BEV * S * (nslice > 0 ? nslice : 1) * KNN);

    hipMemsetAsync(qcount, 0, 64, stream);
    k_event_max<<<BEV, NTH, 0, stream>>>(score, mrss);
    k_thr<<<1, 1, 0, stream>>>(mrss, thr);
    k_sel<<<BEV, NTH, 0, stream>>>(score, coords, thr, counts, qcount, qlist, pts,
                                   out_nidx, out_dist, out_w, out_sel);
    k_rsup<<<1, 1, 0, stream>>>(counts, out_rsup);

    if (nslice > 0) {
        int slen = S / nslice;
        dim3 gk(S / NTH, nslice, BEV);
        k_knn_part<<<gk, NTH, 0, stream>>>(coords, qcount, qlist, pts, pd, pi,
                                           slen, nslice);
        dim3 gm(S / NTH, BEV);
        k_merge<<<gm, NTH, 0, stream>>>(qcount, qlist, pd, pi, nslice,
                                        out_nidx, out_dist, out_w);
    } else {
        k_knn_old<<<BEV * (S / RPB), NTH, 0, stream>>>(coords, score, qcount, qlist,
                                                       out_nidx, out_dist, out_w);
    }
}

// Round 3
// 173.850 us; speedup vs baseline: 1.5722x; 1.1892x over previous
//
#include <hip/hip_runtime.h>
#include <math.h>

#define S      4096
#define BEV    16
#define KNN    5
#define NTH    256
#define BIGF   1.0e9f

__device__ __forceinline__ float fmulrn(float a, float b) { return __fmul_rn(a, b); }
__device__ __forceinline__ float faddrn(float a, float b) { return __fadd_rn(a, b); }

// ---- kernel 1: per-event max score; thr_bits = min over events of bits(0.98*max) ----
// (x0.98 is monotone under rn, so min of products == product of min; clamp to 0.5 at use)
__global__ __launch_bounds__(NTH) void k_max(const float* __restrict__ score,
                                             unsigned int* __restrict__ thr_bits) {
    int b = blockIdx.x;
    const float* s = score + (size_t)b * S;
    float m = -3.0e38f;
    for (int t = threadIdx.x; t < S; t += NTH) m = fmaxf(m, s[t]);
#pragma unroll
    for (int off = 32; off >= 1; off >>= 1) m = fmaxf(m, __shfl_xor(m, off, 64));
    __shared__ float red[NTH / 64];
    if ((threadIdx.x & 63) == 0) red[threadIdx.x >> 6] = m;
    __syncthreads();
    if (threadIdx.x == 0) {
        float mm = red[0];
        for (int w = 1; w < NTH / 64; w++) mm = fmaxf(mm, red[w]);
        atomicMin(thr_bits, __float_as_uint(__fmul_rn(mm, 0.98f)));  // scores>0 -> bits monotone
    }
}

// ---- kernel 2: sel_mask, counts, ORDERED query/candidate compaction, pts prep, defaults ----
__global__ __launch_bounds__(NTH) void k_sel(const float* __restrict__ score,
                                             const float* __restrict__ coords,
                                             const unsigned int* __restrict__ thr_bits,
                                             int* __restrict__ counts,
                                             int* __restrict__ qcount,
                                             int* __restrict__ ccount,
                                             int* __restrict__ qlist,
                                             int* __restrict__ clist,
                                             float4* __restrict__ ptsc,
                                             float4* __restrict__ qpts,
                                             float* __restrict__ out_nidx,
                                             float* __restrict__ out_dist,
                                             float* __restrict__ out_w,
                                             float* __restrict__ out_sel) {
    int b = blockIdx.x, t = threadIdx.x;
    float thr = fminf(__uint_as_float(thr_bits[0]), 0.5f);
    size_t gbase = (size_t)b * S;
    int p0 = t * 16;

    float sc[16];
    int qn = 0, cn = 0, sn = 0;
#pragma unroll
    for (int i = 0; i < 16; i++) {
        float v = score[gbase + p0 + i];
        sc[i] = v;
        bool cand = (v > 0.5f);
        qn += cand ? 0 : 1;
        cn += cand ? 1 : 0;
        sn += (v >= thr) ? 1 : 0;
        out_sel[gbase + p0 + i] = (v >= thr) ? 1.0f : 0.0f;
    }

    // inclusive wave scan of packed (q | c<<16), then cross-wave offsets via LDS
    int pkv = qn | (cn << 16);
    int incl = pkv;
#pragma unroll
    for (int off = 1; off < 64; off <<= 1) {
        int u = __shfl_up(incl, off, 64);
        if ((t & 63) >= off) incl += u;
    }
    __shared__ int wtot[NTH / 64];
    __shared__ int stot[NTH / 64];
    int wid = t >> 6;
    if ((t & 63) == 63) wtot[wid] = incl;
    int ssum = sn;
#pragma unroll
    for (int off = 32; off >= 1; off >>= 1) ssum += __shfl_xor(ssum, off, 64);
    if ((t & 63) == 0) stot[wid] = ssum;
    __syncthreads();
    int base = 0;
    for (int w = 0; w < wid; w++) base += wtot[w];
    int excl = base + incl - pkv;
    int qE = excl & 0xffff;
    int cE = excl >> 16;
    if (t == NTH - 1) {
        int tot = base + incl;
        qcount[b] = tot & 0xffff;
        ccount[b] = tot >> 16;
        counts[b] = stot[0] + stot[1] + stot[2] + stot[3];
    }

#pragma unroll
    for (int i = 0; i < 16; i++) {
        int p = p0 + i;
        size_t gi = gbase + p;
        const float* c = coords + gi * 3;
        float x = c[0], y = c[1], z = c[2];
        float xx = faddrn(faddrn(fmulrn(x, x), fmulrn(y, y)), fmulrn(z, z));
        if (sc[i] > 0.5f) {
            // candidate (direction 0): in KNN pool; outputs are fixed defaults
            clist[gbase + cE] = p;
            ptsc[gbase + cE] = make_float4(fmulrn(-2.0f, x), fmulrn(-2.0f, y),
                                           fmulrn(-2.0f, z), xx);
            cE++;
#pragma unroll
            for (int k = 0; k < KNN; k++) {
                out_nidx[gi * KNN + k] = -1.0f;
                out_dist[gi * KNN + k] = 0.0f;
                out_w[gi * KNN + k]    = 0.2f;
            }
        } else {
            // query (direction 1)
            qlist[gbase + qE] = p;
            qpts[gbase + qE] = make_float4(x, y, z, xx);
            qE++;
        }
    }
}

// ---- kernel 3: sliced KNN over compacted candidates, branchless u64 top-5 ----
__global__ __launch_bounds__(NTH) void k_knn(const float4* __restrict__ ptsc,
                                             const float4* __restrict__ qpts,
                                             const int* __restrict__ qcount,
                                             const int* __restrict__ ccount,
                                             unsigned long long* __restrict__ pk,
                                             int nsl) {
    int b = blockIdx.z, sl = blockIdx.y;
    int r = blockIdx.x * NTH + threadIdx.x;
    int qc = qcount[b];
    if (r >= qc) return;
    int cc = ccount[b];
    int slen = (cc + nsl - 1) / nsl;
    int j0 = sl * slen;
    int j1 = min(j0 + slen, cc);

    float4 q = qpts[(size_t)b * S + r];
    float xi = q.x, yi = q.y, zi = q.z, xxi = q.w;
    const float4* __restrict__ pp = ptsc + (size_t)b * S;

    unsigned long long k0 = ~0ull, k1 = ~0ull, k2 = ~0ull, k3 = ~0ull, k4 = ~0ull;

#pragma unroll 4
    for (int j = j0; j < j1; j++) {
        float4 p = pp[j];   // wave-uniform address
        float dm = faddrn(faddrn(fmulrn(p.x, xi), fmulrn(p.y, yi)), fmulrn(p.z, zi));
        float dd = faddrn(faddrn(xxi, p.w), dm);     // (xx_i+xx_j) - 2*dot, ref rounding
        dd = fmaxf(dd, 0.0f);
        // dd>=0 -> float bits monotone; u64 (bits<<32 | pos) = exact (d, idx) lex order
        unsigned long long t = ((unsigned long long)__float_as_uint(dd) << 32) | (unsigned int)j;
        { bool c = t < k0; unsigned long long lo = c ? t : k0, hi = c ? k0 : t; k0 = lo; t = hi; }
        { bool c = t < k1; unsigned long long lo = c ? t : k1, hi = c ? k1 : t; k1 = lo; t = hi; }
        { bool c = t < k2; unsigned long long lo = c ? t : k2, hi = c ? k2 : t; k2 = lo; t = hi; }
        { bool c = t < k3; unsigned long long lo = c ? t : k3, hi = c ? k3 : t; k3 = lo; t = hi; }
        { bool c = t < k4; unsigned long long lo = c ? t : k4, hi = c ? k4 : t; k4 = lo; t = hi; }
    }

    size_t po = ((size_t)((size_t)b * S + r) * nsl + sl) * KNN;
    pk[po + 0] = k0; pk[po + 1] = k1; pk[po + 2] = k2; pk[po + 3] = k3; pk[po + 4] = k4;
}

// ---- kernel 4: merge slice partials + epilogue (+rs_up by one designated thread) ----
__global__ __launch_bounds__(NTH) void k_merge(const int* __restrict__ qcount,
                                               const int* __restrict__ qlist,
                                               const int* __restrict__ clist,
                                               const unsigned long long* __restrict__ pk,
                                               const int* __restrict__ counts,
                                               int nsl,
                                               float* __restrict__ out_nidx,
                                               float* __restrict__ out_dist,
                                               float* __restrict__ out_w,
                                               float* __restrict__ out_rsup) {
    int b = blockIdx.y;
    int r = blockIdx.x * NTH + threadIdx.x;
    if (b == 0 && blockIdx.x == 0 && threadIdx.x == 0) {
        int acc = 0;
        out_rsup[0] = 0.0f;
        for (int e = 0; e < BEV; e++) { acc += counts[e]; out_rsup[e + 1] = (float)acc; }
    }
    int qc = qcount[b];
    if (r >= qc) return;

    unsigned long long a0 = ~0ull, a1 = ~0ull, a2 = ~0ull, a3 = ~0ull, a4 = ~0ull;
    size_t po = (size_t)((size_t)b * S + r) * nsl * KNN;
    for (int s = 0; s < nsl; s++) {
#pragma unroll
        for (int k = 0; k < KNN; k++) {
            unsigned long long t = pk[po + s * KNN + k];
            // keys unique; ascending within each list; strict-< keeps exact order
            if (t < a4) {
                a4 = t;
                if (a4 < a3) { unsigned long long u = a3; a3 = a4; a4 = u; }
                if (a3 < a2) { unsigned long long u = a2; a2 = a3; a3 = u; }
                if (a2 < a1) { unsigned long long u = a1; a1 = a2; a2 = u; }
                if (a1 < a0) { unsigned long long u = a0; a0 = a1; a1 = u; }
            }
        }
    }

    int irow = qlist[(size_t)b * S + r];
    size_t gi = (size_t)b * S + irow;
    unsigned long long av[KNN] = { a0, a1, a2, a3, a4 };

    float dk[KNN], nk[KNN], e[KNN];
    float m = -3.0e38f;
#pragma unroll
    for (int k = 0; k < KNN; k++) {
        float d = __uint_as_float((unsigned int)(av[k] >> 32));
        bool val = (d < BIGF);                       // NaN sentinel -> false
        int cpos = (int)(av[k] & 0xffffffffu);
        cpos = val ? cpos : 0;                       // clamp to avoid OOB
        if (cpos >= S) cpos = 0;
        dk[k] = val ? d : 0.0f;
        nk[k] = val ? (float)(b * S + clist[(size_t)b * S + cpos]) : -1.0f;
        e[k]  = expf(-dk[k]);
        m = fmaxf(m, e[k]);
    }
    float u[KNN], ssum = 0.0f;
#pragma unroll
    for (int k = 0; k < KNN; k++) { u[k] = expf(e[k] - m); ssum += u[k]; }
#pragma unroll
    for (int k = 0; k < KNN; k++) {
        out_nidx[gi * KNN + k] = nk[k];
        out_dist[gi * KNN + k] = dk[k];
        out_w[gi * KNN + k]    = u[k] / ssum;
    }
}

extern "C" void kernel_launch(void* const* d_in, const int* in_sizes, int n_in,
                              void* d_out, int out_size, void* d_ws, size_t ws_size,
                              hipStream_t stream) {
    const float* score  = (const float*)d_in[0];
    const float* coords = (const float*)d_in[1];

    float* out = (float*)d_out;
    size_t NK = (size_t)BEV * S * KNN;
    float* out_nidx = out;
    float* out_dist = out + NK;
    float* out_w    = out + 2 * NK;
    float* out_rsup = out + 3 * NK;
    float* out_sel  = out + 3 * NK + (BEV + 1);

    char* ws = (char*)d_ws;
    unsigned int* thr_bits = (unsigned int*)(ws);        // 4B @0
    int* counts = (int*)(ws + 64);                       // 16 ints
    int* qcount = (int*)(ws + 128);                      // 16 ints
    int* ccount = (int*)(ws + 192);                      // 16 ints
    int* qlist  = (int*)(ws + 256);                      // BEV*S ints (256KB)
    size_t off_clist = 256 + (size_t)BEV * S * 4;        // 262400
    int* clist = (int*)(ws + off_clist);
    size_t off_ptsc = off_clist + (size_t)BEV * S * 4;   // 524544 (16B aligned)
    float4* ptsc = (float4*)(ws + off_ptsc);
    size_t off_qpts = off_ptsc + (size_t)BEV * S * 16;   // +1MB
    float4* qpts = (float4*)(ws + off_qpts);
    size_t off_pk = off_qpts + (size_t)BEV * S * 16;     // +1MB
    unsigned long long* pk = (unsigned long long*)(ws + off_pk);

    int nsl = 1;
    {
        const int cands[4] = {8, 4, 2, 1};
        for (int c = 0; c < 4; c++) {
            size_t need = off_pk + (size_t)BEV * S * cands[c] * KNN * 8;
            if (ws_size >= need) { nsl = cands[c]; break; }
        }
    }

    hipMemsetAsync(thr_bits, 0x7f, 4, stream);           // +huge init for float-bits min
    k_max<<<BEV, NTH, 0, stream>>>(score, thr_bits);
    k_sel<<<BEV, NTH, 0, stream>>>(score, coords, thr_bits, counts, qcount, ccount,
                                   qlist, clist, ptsc, qpts,
                                   out_nidx, out_dist, out_w, out_sel);
    dim3 gk(S / NTH, nsl, BEV);
    k_knn<<<gk, NTH, 0, stream>>>(ptsc, qpts, qcount, ccount, pk, nsl);
    dim3 gm(S / NTH, BEV);
    k_merge<<<gm, NTH, 0, stream>>>(qcount, qlist, clist, pk, counts, nsl,
                                    out_nidx, out_dist, out_w, out_rsup);
}

// Round 5
// 148.492 us; speedup vs baseline: 1.8407x; 1.1708x over previous
//
#include <hip/hip_runtime.h>
#include <math.h>

#define S      4096
#define BEV    16
#define KNN    5
#define NTH    256
#define NSEL   1024
#define NKNN   64
#define BIGF   1.0e9f

__device__ __forceinline__ float fmulrn(float a, float b) { return __fmul_rn(a, b); }
__device__ __forceinline__ float faddrn(float a, float b) { return __fadd_rn(a, b); }

// ---- kernel 1: per-event max score; thr_bits = min over events of bits(0.98*max) ----
__global__ __launch_bounds__(NSEL) void k_max(const float* __restrict__ score,
                                              unsigned int* __restrict__ thr_bits) {
    int b = blockIdx.x, t = threadIdx.x;
    const float* s = score + (size_t)b * S;
    float m = -3.0e38f;
#pragma unroll
    for (int i = 0; i < S / NSEL; i++) m = fmaxf(m, s[t + i * NSEL]);
#pragma unroll
    for (int off = 32; off >= 1; off >>= 1) m = fmaxf(m, __shfl_xor(m, off, 64));
    __shared__ float red[NSEL / 64];
    if ((t & 63) == 0) red[t >> 6] = m;
    __syncthreads();
    if (t == 0) {
        float mm = red[0];
        for (int w = 1; w < NSEL / 64; w++) mm = fmaxf(mm, red[w]);
        atomicMin(thr_bits, __float_as_uint(__fmul_rn(mm, 0.98f)));  // scores>0: bits monotone
    }
}

// ---- kernel 2: sel_mask, counts, ORDERED query/candidate compaction, pts prep, defaults ----
__global__ __launch_bounds__(NSEL) void k_sel(const float* __restrict__ score,
                                              const float* __restrict__ coords,
                                              const unsigned int* __restrict__ thr_bits,
                                              int* __restrict__ counts,
                                              int* __restrict__ qcount,
                                              int* __restrict__ ccount,
                                              int* __restrict__ qlist,
                                              int* __restrict__ clist,
                                              float4* __restrict__ ptsc,
                                              float4* __restrict__ qpts,
                                              float* __restrict__ out_nidx,
                                              float* __restrict__ out_dist,
                                              float* __restrict__ out_w,
                                              float* __restrict__ out_sel) {
    const int PPT = S / NSEL;                 // 4 points per thread
    int b = blockIdx.x, t = threadIdx.x;
    float thr = fminf(__uint_as_float(thr_bits[0]), 0.5f);
    size_t gbase = (size_t)b * S;
    int p0 = t * PPT;

    float sc[PPT];
    int qn = 0, cn = 0, sn = 0;
#pragma unroll
    for (int i = 0; i < PPT; i++) {
        float v = score[gbase + p0 + i];
        sc[i] = v;
        bool cand = (v > 0.5f);
        qn += cand ? 0 : 1;
        cn += cand ? 1 : 0;
        sn += (v >= thr) ? 1 : 0;
        out_sel[gbase + p0 + i] = (v >= thr) ? 1.0f : 0.0f;
    }

    // inclusive wave scan of packed (q | c<<16), cross-wave offsets via LDS
    int pkv = qn | (cn << 16);
    int incl = pkv;
#pragma unroll
    for (int off = 1; off < 64; off <<= 1) {
        int u = __shfl_up(incl, off, 64);
        if ((t & 63) >= off) incl += u;
    }
    __shared__ int wtot[NSEL / 64];
    __shared__ int stot[NSEL / 64];
    int wid = t >> 6;
    if ((t & 63) == 63) wtot[wid] = incl;
    int ssum = sn;
#pragma unroll
    for (int off = 32; off >= 1; off >>= 1) ssum += __shfl_xor(ssum, off, 64);
    if ((t & 63) == 0) stot[wid] = ssum;
    __syncthreads();
    int base = 0;
    for (int w = 0; w < wid; w++) base += wtot[w];
    int excl = base + incl - pkv;
    int qE = excl & 0xffff;
    int cE = excl >> 16;
    if (t == NSEL - 1) {
        int tot = base + incl;
        qcount[b] = tot & 0xffff;
        ccount[b] = tot >> 16;
        int cs = 0;
        for (int w = 0; w < NSEL / 64; w++) cs += stot[w];
        counts[b] = cs;
    }

#pragma unroll
    for (int i = 0; i < PPT; i++) {
        int p = p0 + i;
        size_t gi = gbase + p;
        const float* c = coords + gi * 3;
        float x = c[0], y = c[1], z = c[2];
        float xx = faddrn(faddrn(fmulrn(x, x), fmulrn(y, y)), fmulrn(z, z));
        if (sc[i] > 0.5f) {
            clist[gbase + cE] = p;
            ptsc[gbase + cE] = make_float4(fmulrn(-2.0f, x), fmulrn(-2.0f, y),
                                           fmulrn(-2.0f, z), xx);
            cE++;
#pragma unroll
            for (int k = 0; k < KNN; k++) {
                out_nidx[gi * KNN + k] = -1.0f;
                out_dist[gi * KNN + k] = 0.0f;
                out_w[gi * KNN + k]    = 0.2f;
            }
        } else {
            qlist[gbase + qE] = p;
            qpts[gbase + qE] = make_float4(x, y, z, xx);
            qE++;
        }
    }
}

// ---- kernel 3: sliced KNN, parallel-compare branchless sorted insert ----
__global__ __launch_bounds__(NKNN) void k_knn(const float4* __restrict__ ptsc,
                                              const float4* __restrict__ qpts,
                                              const int* __restrict__ qcount,
                                              const int* __restrict__ ccount,
                                              unsigned long long* __restrict__ pk,
                                              int nsl) {
    int b = blockIdx.z, sl = blockIdx.y;
    int r = blockIdx.x * NKNN + threadIdx.x;
    int qc = qcount[b];
    if (r >= qc) return;
    int cc = ccount[b];
    int slen = (cc + nsl - 1) / nsl;
    int j0 = sl * slen;
    int j1 = min(j0 + slen, cc);

    float4 q = qpts[(size_t)b * S + r];
    float xi = q.x, yi = q.y, zi = q.z, xxi = q.w;
    const float4* __restrict__ pp = ptsc + (size_t)b * S;

    const float INF = __int_as_float(0x7f800000);
    float d0 = INF, d1 = INF, d2 = INF, d3 = INF, d4 = INF;
    int   i0 = -1, i1 = -1, i2 = -1, i3 = -1, i4 = -1;

#pragma unroll 4
    for (int j = j0; j < j1; j++) {
        float4 p = pp[j];                    // wave-uniform address
        float dm = faddrn(faddrn(fmulrn(p.x, xi), fmulrn(p.y, yi)), fmulrn(p.z, zi));
        float dd = faddrn(faddrn(xxi, p.w), dm);   // (xx_i+xx_j) - 2*dot, ref rounding
        dd = fmaxf(dd, 0.0f);
        // parallel-compare sorted insert; strict < == exact (d, pos) lex order
        // (scan is ascending pos, so equal dd ranks after existing entries)
        bool c0 = dd < d0, c1 = dd < d1, c2 = dd < d2, c3 = dd < d3, c4 = dd < d4;
        d4 = c4 ? (c3 ? d3 : dd) : d4;  i4 = c4 ? (c3 ? i3 : j) : i4;
        d3 = c3 ? (c2 ? d2 : dd) : d3;  i3 = c3 ? (c2 ? i2 : j) : i3;
        d2 = c2 ? (c1 ? d1 : dd) : d2;  i2 = c2 ? (c1 ? i1 : j) : i2;
        d1 = c1 ? (c0 ? d0 : dd) : d1;  i1 = c1 ? (c0 ? i0 : j) : i1;
        d0 = c0 ? dd : d0;              i0 = c0 ? j : i0;
    }

    size_t po = ((size_t)((size_t)b * S + r) * nsl + sl) * KNN;
    pk[po + 0] = ((unsigned long long)__float_as_uint(d0) << 32) | (unsigned int)i0;
    pk[po + 1] = ((unsigned long long)__float_as_uint(d1) << 32) | (unsigned int)i1;
    pk[po + 2] = ((unsigned long long)__float_as_uint(d2) << 32) | (unsigned int)i2;
    pk[po + 3] = ((unsigned long long)__float_as_uint(d3) << 32) | (unsigned int)i3;
    pk[po + 4] = ((unsigned long long)__float_as_uint(d4) << 32) | (unsigned int)i4;
}

// ---- kernel 4: merge slice partials + epilogue (+rs_up by one designated thread) ----
__global__ __launch_bounds__(NTH) void k_merge(const int* __restrict__ qcount,
                                               const int* __restrict__ qlist,
                                               const int* __restrict__ clist,
                                               const unsigned long long* __restrict__ pk,
                                               const int* __restrict__ counts,
                                               int nsl,
                                               float* __restrict__ out_nidx,
                                               float* __restrict__ out_dist,
                                               float* __restrict__ out_w,
                                               float* __restrict__ out_rsup) {
    int b = blockIdx.y;
    int r = blockIdx.x * NTH + threadIdx.x;
    if (b == 0 && blockIdx.x == 0 && threadIdx.x == 0) {
        int acc = 0;
        out_rsup[0] = 0.0f;
        for (int e = 0; e < BEV; e++) { acc += counts[e]; out_rsup[e + 1] = (float)acc; }
    }
    int qc = qcount[b];
    if (r >= qc) return;

    unsigned long long a0 = ~0ull, a1 = ~0ull, a2 = ~0ull, a3 = ~0ull, a4 = ~0ull;
    size_t po = (size_t)((size_t)b * S + r) * nsl * KNN;
    for (int s = 0; s < nsl; s++) {
#pragma unroll
        for (int k = 0; k < KNN; k++) {
            unsigned long long t = pk[po + s * KNN + k];
            if (t < a4) {
                a4 = t;
                if (a4 < a3) { unsigned long long u = a3; a3 = a4; a4 = u; }
                if (a3 < a2) { unsigned long long u = a2; a2 = a3; a3 = u; }
                if (a2 < a1) { unsigned long long u = a1; a1 = a2; a2 = u; }
                if (a1 < a0) { unsigned long long u = a0; a0 = a1; a1 = u; }
            }
        }
    }

    int irow = qlist[(size_t)b * S + r];
    size_t gi = (size_t)b * S + irow;
    unsigned long long av[KNN] = { a0, a1, a2, a3, a4 };

    float dk[KNN], nk[KNN], e[KNN];
    float m = -3.0e38f;
#pragma unroll
    for (int k = 0; k < KNN; k++) {
        float d = __uint_as_float((unsigned int)(av[k] >> 32));
        bool val = (d < BIGF);
        int cpos = (int)(av[k] & 0xffffffffu);
        cpos = val ? cpos : 0;
        if (cpos >= S) cpos = 0;
        dk[k] = val ? d : 0.0f;
        nk[k] = val ? (float)(b * S + clist[(size_t)b * S + cpos]) : -1.0f;
        e[k]  = expf(-dk[k]);
        m = fmaxf(m, e[k]);
    }
    float u[KNN], ssum = 0.0f;
#pragma unroll
    for (int k = 0; k < KNN; k++) { u[k] = expf(e[k] - m); ssum += u[k]; }
#pragma unroll
    for (int k = 0; k < KNN; k++) {
        out_nidx[gi * KNN + k] = nk[k];
        out_dist[gi * KNN + k] = dk[k];
        out_w[gi * KNN + k]    = u[k] / ssum;
    }
}

extern "C" void kernel_launch(void* const* d_in, const int* in_sizes, int n_in,
                              void* d_out, int out_size, void* d_ws, size_t ws_size,
                              hipStream_t stream) {
    const float* score  = (const float*)d_in[0];
    const float* coords = (const float*)d_in[1];

    float* out = (float*)d_out;
    size_t NK = (size_t)BEV * S * KNN;
    float* out_nidx = out;
    float* out_dist = out + NK;
    float* out_w    = out + 2 * NK;
    float* out_rsup = out + 3 * NK;
    float* out_sel  = out + 3 * NK + (BEV + 1);

    char* ws = (char*)d_ws;
    unsigned int* thr_bits = (unsigned int*)(ws);        // 4B @0
    int* counts = (int*)(ws + 64);                       // 16 ints
    int* qcount = (int*)(ws + 128);                      // 16 ints
    int* ccount = (int*)(ws + 192);                      // 16 ints
    int* qlist  = (int*)(ws + 256);                      // BEV*S ints (256KB)
    size_t off_clist = 256 + (size_t)BEV * S * 4;
    int* clist = (int*)(ws + off_clist);
    size_t off_ptsc = off_clist + (size_t)BEV * S * 4;   // 16B aligned
    float4* ptsc = (float4*)(ws + off_ptsc);
    size_t off_qpts = off_ptsc + (size_t)BEV * S * 16;
    float4* qpts = (float4*)(ws + off_qpts);
    size_t off_pk = off_qpts + (size_t)BEV * S * 16;
    unsigned long long* pk = (unsigned long long*)(ws + off_pk);

    int nsl = 1;
    {
        const int cands[4] = {8, 4, 2, 1};
        for (int c = 0; c < 4; c++) {
            size_t need = off_pk + (size_t)BEV * S * cands[c] * KNN * 8;
            if (ws_size >= need) { nsl = cands[c]; break; }
        }
    }

    hipMemsetAsync(thr_bits, 0x7f, 4, stream);
    k_max<<<BEV, NSEL, 0, stream>>>(score, thr_bits);
    k_sel<<<BEV, NSEL, 0, stream>>>(score, coords, thr_bits, counts, qcount, ccount,
                                    qlist, clist, ptsc, qpts,
                                    out_nidx, out_dist, out_w, out_sel);
    dim3 gk(S / NKNN, nsl, BEV);
    k_knn<<<gk, NKNN, 0, stream>>>(ptsc, qpts, qcount, ccount, pk, nsl);
    dim3 gm(S / NTH, BEV);
    k_merge<<<gm, NTH, 0, stream>>>(qcount, qlist, clist, pk, counts, nsl,
                                    out_nidx, out_dist, out_w, out_rsup);
}

// Round 8
// 109.443 us; speedup vs baseline: 2.4975x; 1.3568x over previous
//
#include <hip/hip_runtime.h>
#include <math.h>

#define S      4096
#define BEV    16
#define KNN    5
#define BIGF   1.0e9f
#define NSL    32           // slices per candidate scan
#define GPP    16           // query-pairs per knn block
#define PSTRIDE 321         // u64 LDS stride per pair (32*10 + 1 pad)

__device__ __forceinline__ float fmulrn(float a, float b) { return __fmul_rn(a, b); }
__device__ __forceinline__ float faddrn(float a, float b) { return __fadd_rn(a, b); }
__device__ __forceinline__ unsigned long long packk(float d, int i) {
    return ((unsigned long long)__float_as_uint(d) << 32) | (unsigned int)i;
}

// ---- K1: per-(event,chunk) score stats: event max (atomicMax on bits), q/c counts ----
__global__ __launch_bounds__(1024) void k_scan(const float* __restrict__ score,
                                               unsigned int* __restrict__ mrss_bits,
                                               int* __restrict__ qn, int* __restrict__ cn) {
    int blk = blockIdx.x, t = threadIdx.x;
    int b = blk >> 2, ch = blk & 3;
    float v = score[(size_t)b * S + ch * 1024 + t];
    float m = v;
    int pk = (v > 0.5f) ? (1 << 16) : 1;
#pragma unroll
    for (int off = 32; off >= 1; off >>= 1) {
        m = fmaxf(m, __shfl_xor(m, off, 64));
        pk += __shfl_xor(pk, off, 64);
    }
    __shared__ float wm[16];
    __shared__ int wp[16];
    int wid = t >> 6;
    if ((t & 63) == 0) { wm[wid] = m; wp[wid] = pk; }
    __syncthreads();
    if (t == 0) {
        float mm = wm[0]; int pp = wp[0];
        for (int w = 1; w < 16; w++) { mm = fmaxf(mm, wm[w]); pp += wp[w]; }
        atomicMax(&mrss_bits[b], __float_as_uint(mm));   // scores>0: bits monotone
        qn[blk] = pp & 0xffff;
        cn[blk] = pp >> 16;
    }
}

// ---- K2: threshold + all prefix offsets (single thread; tiny) ----
__global__ void k_off(const unsigned int* __restrict__ mrss_bits,
                      const int* __restrict__ qn, const int* __restrict__ cn,
                      float* __restrict__ thrv,
                      int* __restrict__ qchoff, int* __restrict__ cchoff,
                      int* __restrict__ qcount, int* __restrict__ ccount,
                      int* __restrict__ qpoff) {
    if (threadIdx.x != 0) return;
    unsigned int um = mrss_bits[0];
    for (int b = 1; b < BEV; b++) um = min(um, mrss_bits[b]);
    // rn(0.98*x) monotone => min of products == product of min; clamp 0.5
    thrv[0] = fminf(__fmul_rn(__uint_as_float(um), 0.98f), 0.5f);
    int qp = 0;
    for (int b = 0; b < BEV; b++) {
        int qq = 0, cc = 0;
        for (int ch = 0; ch < 4; ch++) {
            qchoff[b * 4 + ch] = qq; cchoff[b * 4 + ch] = cc;
            qq += qn[b * 4 + ch];    cc += cn[b * 4 + ch];
        }
        qcount[b] = qq; ccount[b] = cc;
        qpoff[b] = qp; qp += (qq + 1) >> 1;      // pairs of query rows
    }
    qpoff[BEV] = qp;
}

// ---- K3: ordered compaction (chunked), sel_mask, sel-count atomicAdd ----
__global__ __launch_bounds__(1024) void k_sel(const float* __restrict__ score,
                                              const float* __restrict__ coords,
                                              const float* __restrict__ thrv,
                                              const int* __restrict__ qchoff,
                                              const int* __restrict__ cchoff,
                                              int* __restrict__ counts,
                                              int* __restrict__ qlist,
                                              int* __restrict__ clist,
                                              float4* __restrict__ qpts,
                                              float4* __restrict__ ptsc,
                                              float* __restrict__ out_sel) {
    int blk = blockIdx.x, t = threadIdx.x;
    int b = blk >> 2, ch = blk & 3;
    int p = ch * 1024 + t;
    size_t gi = (size_t)b * S + p;
    float v = score[gi];
    float thr = thrv[0];
    out_sel[gi] = (v >= thr) ? 1.0f : 0.0f;
    bool cand = (v > 0.5f);
    int pk = cand ? (1 << 16) : 1;
    int incl = pk;
#pragma unroll
    for (int off = 1; off < 64; off <<= 1) {
        int u = __shfl_up(incl, off, 64);
        if ((t & 63) >= off) incl += u;
    }
    __shared__ int wtot[16];
    __shared__ int wsel[16];
    int wid = t >> 6;
    if ((t & 63) == 63) wtot[wid] = incl;
    int sel = (v >= thr) ? 1 : 0;
#pragma unroll
    for (int off = 32; off >= 1; off >>= 1) sel += __shfl_xor(sel, off, 64);
    if ((t & 63) == 0) wsel[wid] = sel;
    __syncthreads();
    int base = 0;
    for (int w = 0; w < wid; w++) base += wtot[w];
    int excl = base + incl - pk;
    if (t == 0) {
        int sc2 = 0;
        for (int w = 0; w < 16; w++) sc2 += wsel[w];
        atomicAdd(&counts[b], sc2);
    }
    const float* c = coords + gi * 3;
    float x = c[0], y = c[1], z = c[2];
    float xx = faddrn(faddrn(fmulrn(x, x), fmulrn(y, y)), fmulrn(z, z));
    size_t ebase = (size_t)b * S;
    if (cand) {
        int pos = cchoff[blk] + (excl >> 16);
        clist[ebase + pos] = p;
        ptsc[ebase + pos] = make_float4(fmulrn(-2.0f, x), fmulrn(-2.0f, y),
                                        fmulrn(-2.0f, z), xx);
    } else {
        int pos = qchoff[blk] + (excl & 0xffff);
        qlist[ebase + pos] = p;
        qpts[ebase + pos] = make_float4(x, y, z, xx);
    }
}

// ---- K4: vectorized default fill (-1 / 0 / 0.2) + rs_up prefix ----
__global__ __launch_bounds__(256) void k_fill(float4* __restrict__ out4,
                                              const int* __restrict__ counts,
                                              float* __restrict__ out_rsup) {
    int idx = blockIdx.x * 256 + threadIdx.x;       // 0..61439
    if (blockIdx.x == 0 && threadIdx.x == 0) {
        int acc = 0;
        out_rsup[0] = 0.0f;
        for (int e = 0; e < BEV; e++) { acc += counts[e]; out_rsup[e + 1] = (float)acc; }
    }
    const int R = BEV * S * KNN / 4;                 // 81920 float4 per region
#pragma unroll
    for (int i = 0; i < 4; i++) {
        int s = idx + i * 61440;
        float val = (s < R) ? -1.0f : ((s < 2 * R) ? 0.0f : 0.2f);
        out4[s] = make_float4(val, val, val, val);
    }
}

// ---- K5: fused KNN: 2 rows/thread x 32 slices, LDS merge + epilogue ----
__global__ __launch_bounds__(512) void k_knn(const float4* __restrict__ ptsc,
                                             const float4* __restrict__ qpts,
                                             const int* __restrict__ qlist,
                                             const int* __restrict__ clist,
                                             const int* __restrict__ qpoff,
                                             const int* __restrict__ qcount,
                                             const int* __restrict__ ccount,
                                             float* __restrict__ out_nidx,
                                             float* __restrict__ out_dist,
                                             float* __restrict__ out_w) {
    int pg = blockIdx.x, t = threadIdx.x;
    int total = qpoff[BEV];
    if (pg * GPP >= total) return;                   // uniform exit, before barriers

    __shared__ int sqp[BEV + 1];
    __shared__ int sqc[BEV];
    __shared__ int scc[BEV];
    __shared__ unsigned long long part[GPP * PSTRIDE];
    if (t < BEV + 1) sqp[t] = qpoff[t];
    if (t < BEV) { sqc[t] = qcount[t]; scc[t] = ccount[t]; }
    __syncthreads();

    int pr = t & 15, sl = t >> 4;
    int gpr = pg * GPP + pr;
    bool pact = gpr < total;
    int gp = pact ? gpr : (total - 1);
    int b = 0;
#pragma unroll
    for (int e = 1; e < BEV; e++) b += (gp >= sqp[e]) ? 1 : 0;
    int rp = gp - sqp[b];
    int qc = sqc[b], cc = scc[b];
    int r0 = 2 * rp, r1 = r0 + 1;
    bool a1v = pact && (r1 < qc);
    size_t ebase = (size_t)b * S;
    float4 q0 = qpts[ebase + r0];
    float4 q1 = qpts[ebase + (a1v ? r1 : r0)];

    int slen = (cc + NSL - 1) / NSL;
    int j0 = sl * slen;
    int j1 = min(j0 + slen, cc);

    const float INF = __int_as_float(0x7f800000);
    float A0=INF,A1=INF,A2=INF,A3=INF,A4=INF; int IA0=-1,IA1=-1,IA2=-1,IA3=-1,IA4=-1;
    float B0=INF,B1=INF,B2=INF,B3=INF,B4=INF; int IB0=-1,IB1=-1,IB2=-1,IB3=-1,IB4=-1;
    const float4* __restrict__ pp = ptsc + ebase;

#pragma unroll 2
    for (int j = j0; j < j1; j++) {
        float4 p = pp[j];       // shared across both rows; 4 addrs per wave
        float dm0 = faddrn(faddrn(fmulrn(p.x, q0.x), fmulrn(p.y, q0.y)), fmulrn(p.z, q0.z));
        float dd0 = fmaxf(faddrn(faddrn(q0.w, p.w), dm0), 0.0f);
        float dm1 = faddrn(faddrn(fmulrn(p.x, q1.x), fmulrn(p.y, q1.y)), fmulrn(p.z, q1.z));
        float dd1 = fmaxf(faddrn(faddrn(q1.w, p.w), dm1), 0.0f);
        { bool c0=dd0<A0,c1=dd0<A1,c2=dd0<A2,c3=dd0<A3,c4=dd0<A4;
          A4=c4?(c3?A3:dd0):A4; IA4=c4?(c3?IA3:j):IA4;
          A3=c3?(c2?A2:dd0):A3; IA3=c3?(c2?IA2:j):IA3;
          A2=c2?(c1?A1:dd0):A2; IA2=c2?(c1?IA1:j):IA2;
          A1=c1?(c0?A0:dd0):A1; IA1=c1?(c0?IA0:j):IA1;
          A0=c0?dd0:A0;         IA0=c0?j:IA0; }
        { bool c0=dd1<B0,c1=dd1<B1,c2=dd1<B2,c3=dd1<B3,c4=dd1<B4;
          B4=c4?(c3?B3:dd1):B4; IB4=c4?(c3?IB3:j):IB4;
          B3=c3?(c2?B2:dd1):B3; IB3=c3?(c2?IB2:j):IB3;
          B2=c2?(c1?B1:dd1):B2; IB2=c2?(c1?IB1:j):IB2;
          B1=c1?(c0?B0:dd1):B1; IB1=c1?(c0?IB0:j):IB1;
          B0=c0?dd1:B0;         IB0=c0?j:IB0; }
    }

    unsigned long long* wp2 = &part[pr * PSTRIDE + sl * 10];
    wp2[0] = packk(A0, IA0); wp2[1] = packk(A1, IA1); wp2[2] = packk(A2, IA2);
    wp2[3] = packk(A3, IA3); wp2[4] = packk(A4, IA4);
    wp2[5] = packk(B0, IB0); wp2[6] = packk(B1, IB1); wp2[7] = packk(B2, IB2);
    wp2[8] = packk(B3, IB3); wp2[9] = packk(B4, IB4);
    __syncthreads();

    if (t < 2 * GPP) {
        int pr2 = t >> 1, rs = t & 1;
        int gpr2 = pg * GPP + pr2;
        bool pact2 = gpr2 < total;
        int gp2 = pact2 ? gpr2 : (total - 1);
        int b2 = 0;
#pragma unroll
        for (int e = 1; e < BEV; e++) b2 += (gp2 >= sqp[e]) ? 1 : 0;
        int rp2 = gp2 - sqp[b2];
        int qc2 = sqc[b2];
        int r = 2 * rp2 + rs;
        bool valid = pact2 && (r < qc2);
        unsigned long long a0=~0ull, a1u=~0ull, a2u=~0ull, a3u=~0ull, a4u=~0ull;
        const unsigned long long* rb = &part[pr2 * PSTRIDE + rs * 5];
        for (int s2 = 0; s2 < NSL; s2++) {
#pragma unroll
            for (int k = 0; k < KNN; k++) {
                unsigned long long key = rb[s2 * 10 + k];
                if (key < a4u) {
                    a4u = key;
                    if (a4u < a3u) { unsigned long long u = a3u; a3u = a4u; a4u = u; }
                    if (a3u < a2u) { unsigned long long u = a2u; a2u = a3u; a3u = u; }
                    if (a2u < a1u) { unsigned long long u = a1u; a1u = a2u; a2u = u; }
                    if (a1u < a0)  { unsigned long long u = a0;  a0  = a1u; a1u = u; }
                }
            }
        }
        if (valid) {
            size_t eb2 = (size_t)b2 * S;
            int irow = qlist[eb2 + r];
            size_t gi = eb2 + irow;
            unsigned long long av[KNN] = {a0, a1u, a2u, a3u, a4u};
            float dk[KNN], nk[KNN], ev[KNN];
            float m = -3.0e38f;
#pragma unroll
            for (int k = 0; k < KNN; k++) {
                float d = __uint_as_float((unsigned int)(av[k] >> 32));
                bool val = (d < BIGF);
                int cpos = (int)(unsigned int)(av[k] & 0xffffffffu);
                if (!val || cpos >= S || cpos < 0) cpos = 0;
                dk[k] = val ? d : 0.0f;
                nk[k] = val ? (float)(b2 * S + clist[eb2 + cpos]) : -1.0f;
                ev[k] = expf(-dk[k]);
                m = fmaxf(m, ev[k]);
            }
            float u[KNN], ssum = 0.0f;
#pragma unroll
            for (int k = 0; k < KNN; k++) { u[k] = expf(ev[k] - m); ssum += u[k]; }
#pragma unroll
            for (int k = 0; k < KNN; k++) {
                out_nidx[gi * KNN + k] = nk[k];
                out_dist[gi * KNN + k] = dk[k];
                out_w[gi * KNN + k]    = u[k] / ssum;
            }
        }
    }
}

extern "C" void kernel_launch(void* const* d_in, const int* in_sizes, int n_in,
                              void* d_out, int out_size, void* d_ws, size_t ws_size,
                              hipStream_t stream) {
    const float* score  = (const float*)d_in[0];
    const float* coords = (const float*)d_in[1];

    float* out = (float*)d_out;
    size_t NK = (size_t)BEV * S * KNN;
    float* out_nidx = out;
    float* out_dist = out + NK;
    float* out_w    = out + 2 * NK;
    float* out_rsup = out + 3 * NK;
    float* out_sel  = out + 3 * NK + (BEV + 1);

    char* ws = (char*)d_ws;
    unsigned int* mrss_bits = (unsigned int*)(ws + 0);    // 16 u32
    float* thrv   = (float*)(ws + 64);
    int* qn       = (int*)(ws + 128);                     // 64
    int* cn       = (int*)(ws + 384);                     // 64
    int* qchoff   = (int*)(ws + 640);                     // 64
    int* cchoff   = (int*)(ws + 896);                     // 64
    int* qcount   = (int*)(ws + 1152);                    // 16
    int* ccount   = (int*)(ws + 1216);                    // 16
    int* counts   = (int*)(ws + 1280);                    // 16
    int* qpoff    = (int*)(ws + 1344);                    // 17
    int* qlist    = (int*)(ws + 2048);                    // BEV*S
    int* clist    = (int*)(ws + 2048 + (size_t)BEV * S * 4);
    float4* qpts  = (float4*)(ws + 2048 + (size_t)BEV * S * 8);      // 16B aligned
    float4* ptsc  = (float4*)(ws + 2048 + (size_t)BEV * S * 8 + (size_t)BEV * S * 16);

    hipMemsetAsync(ws, 0, 2048, stream);   // zero mrss_bits + counts (+ small tables)
    k_scan<<<BEV * 4, 1024, 0, stream>>>(score, mrss_bits, qn, cn);
    k_off<<<1, 64, 0, stream>>>(mrss_bits, qn, cn, thrv, qchoff, cchoff,
                                qcount, ccount, qpoff);
    k_sel<<<BEV * 4, 1024, 0, stream>>>(score, coords, thrv, qchoff, cchoff, counts,
                                        qlist, clist, qpts, ptsc, out_sel);
    k_fill<<<240, 256, 0, stream>>>((float4*)out, counts, out_rsup);
    k_knn<<<(BEV * ((S + 1) / 2) + GPP - 1) / GPP, 512, 0, stream>>>(
        ptsc, qpts, qlist, clist, qpoff, qcount, ccount,
        out_nidx, out_dist, out_w);
}

// Round 9
// 98.145 us; speedup vs baseline: 2.7850x; 1.1151x over previous
//
#include <hip/hip_runtime.h>
#include <math.h>

#define S      4096
#define BEV    16
#define KNN    5
#define BIGF   1.0e9f
#define NSL    32           // slices per candidate scan
#define GPP    8            // query-pairs per knn block
#define NTH    256          // = GPP * NSL
#define PSTR   321          // per-pair LDS stride in elements (NSL*10 + 1 pad)

__device__ __forceinline__ float fmulrn(float a, float b) { return __fmul_rn(a, b); }
__device__ __forceinline__ float faddrn(float a, float b) { return __fadd_rn(a, b); }

// ---- K1: per-(event,chunk) stats: chunk max score, query/cand counts (no atomics) ----
__global__ __launch_bounds__(1024) void k_scan(const float* __restrict__ score,
                                               float* __restrict__ mrss4,
                                               int* __restrict__ qn, int* __restrict__ cn) {
    int blk = blockIdx.x, t = threadIdx.x;
    int b = blk >> 2, ch = blk & 3;
    float v = score[(size_t)b * S + ch * 1024 + t];
    float m = v;
    int pk = (v > 0.5f) ? (1 << 16) : 1;
#pragma unroll
    for (int off = 32; off >= 1; off >>= 1) {
        m = fmaxf(m, __shfl_xor(m, off, 64));
        pk += __shfl_xor(pk, off, 64);
    }
    __shared__ float wm[16];
    __shared__ int wp[16];
    int wid = t >> 6;
    if ((t & 63) == 0) { wm[wid] = m; wp[wid] = pk; }
    __syncthreads();
    if (t == 0) {
        float mm = wm[0]; int pp = wp[0];
        for (int w = 1; w < 16; w++) { mm = fmaxf(mm, wm[w]); pp += wp[w]; }
        mrss4[blk] = mm;
        qn[blk] = pp & 0xffff;
        cn[blk] = pp >> 16;
    }
}

// ---- K2: threshold + prefix offsets (single thread; tiny) ----
__global__ void k_off(const float* __restrict__ mrss4,
                      const int* __restrict__ qn, const int* __restrict__ cn,
                      float* __restrict__ thrv,
                      int* __restrict__ qchoff, int* __restrict__ cchoff,
                      int* __restrict__ qcount, int* __restrict__ ccount,
                      int* __restrict__ qpoff) {
    if (threadIdx.x != 0) return;
    float mn = 3.0e38f;
    for (int b = 0; b < BEV; b++) {
        float mx = mrss4[b * 4];
        for (int ch = 1; ch < 4; ch++) mx = fmaxf(mx, mrss4[b * 4 + ch]);
        mn = fminf(mn, mx);
    }
    // rn(0.98*x) monotone => min of products == product of min; clamp 0.5
    thrv[0] = fminf(__fmul_rn(mn, 0.98f), 0.5f);
    int qp = 0;
    for (int b = 0; b < BEV; b++) {
        int qq = 0, cc = 0;
        for (int ch = 0; ch < 4; ch++) {
            qchoff[b * 4 + ch] = qq; cchoff[b * 4 + ch] = cc;
            qq += qn[b * 4 + ch];    cc += cn[b * 4 + ch];
        }
        qcount[b] = qq; ccount[b] = cc;
        qpoff[b] = qp; qp += (qq + 1) >> 1;      // pairs of query rows
    }
    qpoff[BEV] = qp;
}

// ---- K3: ordered compaction + sel_mask + candidate defaults + sel counts ----
__global__ __launch_bounds__(1024) void k_sel(const float* __restrict__ score,
                                              const float* __restrict__ coords,
                                              const float* __restrict__ thrv,
                                              const int* __restrict__ qchoff,
                                              const int* __restrict__ cchoff,
                                              int* __restrict__ scount,
                                              int* __restrict__ qlist,
                                              int* __restrict__ clist,
                                              float4* __restrict__ qpts,
                                              float4* __restrict__ ptsc,
                                              float* __restrict__ out_nidx,
                                              float* __restrict__ out_dist,
                                              float* __restrict__ out_w,
                                              float* __restrict__ out_sel) {
    int blk = blockIdx.x, t = threadIdx.x;
    int b = blk >> 2, ch = blk & 3;
    int p = ch * 1024 + t;
    size_t gi = (size_t)b * S + p;
    float v = score[gi];
    float thr = thrv[0];
    out_sel[gi] = (v >= thr) ? 1.0f : 0.0f;
    bool cand = (v > 0.5f);
    int pk = cand ? (1 << 16) : 1;
    int incl = pk;
#pragma unroll
    for (int off = 1; off < 64; off <<= 1) {
        int u = __shfl_up(incl, off, 64);
        if ((t & 63) >= off) incl += u;
    }
    __shared__ int wtot[16];
    __shared__ int wsel[16];
    int wid = t >> 6;
    if ((t & 63) == 63) wtot[wid] = incl;
    int sel = (v >= thr) ? 1 : 0;
#pragma unroll
    for (int off = 32; off >= 1; off >>= 1) sel += __shfl_xor(sel, off, 64);
    if ((t & 63) == 0) wsel[wid] = sel;
    __syncthreads();
    int base = 0;
    for (int w = 0; w < wid; w++) base += wtot[w];
    int excl = base + incl - pk;
    if (t == 0) {
        int sc2 = 0;
        for (int w = 0; w < 16; w++) sc2 += wsel[w];
        scount[blk] = sc2;
    }
    const float* c = coords + gi * 3;
    float x = c[0], y = c[1], z = c[2];
    float xx = faddrn(faddrn(fmulrn(x, x), fmulrn(y, y)), fmulrn(z, z));
    size_t ebase = (size_t)b * S;
    if (cand) {
        int pos = cchoff[blk] + (excl >> 16);
        clist[ebase + pos] = p;
        ptsc[ebase + pos] = make_float4(fmulrn(-2.0f, x), fmulrn(-2.0f, y),
                                        fmulrn(-2.0f, z), xx);
        // direction-0 rows: fixed default outputs
#pragma unroll
        for (int k = 0; k < KNN; k++) {
            out_nidx[gi * KNN + k] = -1.0f;
            out_dist[gi * KNN + k] = 0.0f;
            out_w[gi * KNN + k]    = 0.2f;
        }
    } else {
        int pos = qchoff[blk] + (excl & 0xffff);
        qlist[ebase + pos] = p;
        qpts[ebase + pos] = make_float4(x, y, z, xx);
    }
}

// ---- K4: fused KNN: 2 rows/thread x 32 slices, med3 insert, LDS merge + epilogue ----
__global__ __launch_bounds__(NTH, 8) void k_knn(const float4* __restrict__ ptsc,
                                                const float4* __restrict__ qpts,
                                                const int* __restrict__ qlist,
                                                const int* __restrict__ clist,
                                                const int* __restrict__ qpoff,
                                                const int* __restrict__ qcount,
                                                const int* __restrict__ ccount,
                                                const int* __restrict__ scount,
                                                float* __restrict__ out_nidx,
                                                float* __restrict__ out_dist,
                                                float* __restrict__ out_w,
                                                float* __restrict__ out_rsup) {
    int pg = blockIdx.x, t = threadIdx.x;
    if (pg == 0 && t == 0) {                     // rs_up prefix (17 floats)
        int acc = 0;
        out_rsup[0] = 0.0f;
        for (int e = 0; e < BEV; e++) {
            acc += scount[e * 4] + scount[e * 4 + 1] + scount[e * 4 + 2] + scount[e * 4 + 3];
            out_rsup[e + 1] = (float)acc;
        }
    }
    int total = qpoff[BEV];
    if (pg * GPP >= total) return;               // uniform exit

    __shared__ int sqp[BEV + 1];
    __shared__ int sqc[BEV];
    __shared__ int scc[BEV];
    __shared__ float dpart[GPP * PSTR];          // 10272 B
    __shared__ unsigned short ipart[GPP * PSTR]; // 5136 B
    if (t < BEV + 1) sqp[t] = qpoff[t];
    if (t < BEV) { sqc[t] = qcount[t]; scc[t] = ccount[t]; }
    __syncthreads();

    int pr = t & (GPP - 1), sl = t >> 3;         // 8 pairs x 32 slices
    int gpr = pg * GPP + pr;
    bool pact = gpr < total;
    int gp = pact ? gpr : (total - 1);
    int b = 0;
#pragma unroll
    for (int e = 1; e < BEV; e++) b += (gp >= sqp[e]) ? 1 : 0;
    int rp = gp - sqp[b];
    int qc = sqc[b], cc = scc[b];
    int r0 = 2 * rp, r1 = r0 + 1;
    bool a1v = pact && (r1 < qc);
    size_t ebase = (size_t)b * S;
    float4 q0 = qpts[ebase + r0];
    float4 q1 = qpts[ebase + (a1v ? r1 : r0)];

    int slen = (cc + NSL - 1) / NSL;
    int j0 = sl * slen;
    int j1 = min(j0 + slen, cc);

    const float INF = __int_as_float(0x7f800000);
    float A0=INF,A1=INF,A2=INF,A3=INF,A4=INF; int IA0=-1,IA1=-1,IA2=-1,IA3=-1,IA4=-1;
    float B0=INF,B1=INF,B2=INF,B3=INF,B4=INF; int IB0=-1,IB1=-1,IB2=-1,IB3=-1,IB4=-1;
    const float4* __restrict__ pp = ptsc + ebase;

#pragma unroll 2
    for (int j = j0; j < j1; j++) {
        float4 p = pp[j];                        // 8 distinct addrs per wave
        float dm0 = faddrn(faddrn(fmulrn(p.x, q0.x), fmulrn(p.y, q0.y)), fmulrn(p.z, q0.z));
        float dd0 = fmaxf(faddrn(faddrn(q0.w, p.w), dm0), 0.0f);
        float dm1 = faddrn(faddrn(fmulrn(p.x, q1.x), fmulrn(p.y, q1.y)), fmulrn(p.z, q1.z));
        float dd1 = fmaxf(faddrn(faddrn(q1.w, p.w), dm1), 0.0f);
        {   // sorted insert: compares (old values) drive idx; med3 updates values
            bool c0=dd0<A0,c1=dd0<A1,c2=dd0<A2,c3=dd0<A3,c4=dd0<A4;
            IA4=c4?(c3?IA3:j):IA4; IA3=c3?(c2?IA2:j):IA3; IA2=c2?(c1?IA1:j):IA2;
            IA1=c1?(c0?IA0:j):IA1; IA0=c0?j:IA0;
            A4=__builtin_amdgcn_fmed3f(dd0,A3,A4); A3=__builtin_amdgcn_fmed3f(dd0,A2,A3);
            A2=__builtin_amdgcn_fmed3f(dd0,A1,A2); A1=__builtin_amdgcn_fmed3f(dd0,A0,A1);
            A0=fminf(A0,dd0);
        }
        {
            bool c0=dd1<B0,c1=dd1<B1,c2=dd1<B2,c3=dd1<B3,c4=dd1<B4;
            IB4=c4?(c3?IB3:j):IB4; IB3=c3?(c2?IB2:j):IB3; IB2=c2?(c1?IB1:j):IB2;
            IB1=c1?(c0?IB0:j):IB1; IB0=c0?j:IB0;
            B4=__builtin_amdgcn_fmed3f(dd1,B3,B4); B3=__builtin_amdgcn_fmed3f(dd1,B2,B3);
            B2=__builtin_amdgcn_fmed3f(dd1,B1,B2); B1=__builtin_amdgcn_fmed3f(dd1,B0,B1);
            B0=fminf(B0,dd1);
        }
    }

    float* wd = &dpart[pr * PSTR + sl * 10];
    unsigned short* wi = &ipart[pr * PSTR + sl * 10];
    wd[0]=A0; wd[1]=A1; wd[2]=A2; wd[3]=A3; wd[4]=A4;
    wd[5]=B0; wd[6]=B1; wd[7]=B2; wd[8]=B3; wd[9]=B4;
    wi[0]=(unsigned short)(IA0-j0); wi[1]=(unsigned short)(IA1-j0);
    wi[2]=(unsigned short)(IA2-j0); wi[3]=(unsigned short)(IA3-j0);
    wi[4]=(unsigned short)(IA4-j0);
    wi[5]=(unsigned short)(IB0-j0); wi[6]=(unsigned short)(IB1-j0);
    wi[7]=(unsigned short)(IB2-j0); wi[8]=(unsigned short)(IB3-j0);
    wi[9]=(unsigned short)(IB4-j0);
    __syncthreads();

    if (t < 2 * GPP) {                           // 16 merge threads
        int pr2 = t >> 1, rs = t & 1;
        int gpr2 = pg * GPP + pr2;
        bool pact2 = gpr2 < total;
        int gp2 = pact2 ? gpr2 : (total - 1);
        int b2 = 0;
#pragma unroll
        for (int e = 1; e < BEV; e++) b2 += (gp2 >= sqp[e]) ? 1 : 0;
        int rp2 = gp2 - sqp[b2];
        int qc2 = sqc[b2], cc2 = scc[b2];
        int slen2 = (cc2 + NSL - 1) / NSL;
        int r = 2 * rp2 + rs;
        bool valid = pact2 && (r < qc2);

        unsigned long long a0=~0ull, a1u=~0ull, a2u=~0ull, a3u=~0ull, a4u=~0ull;
        const float* dp = &dpart[pr2 * PSTR + rs * 5];
        const unsigned short* ip = &ipart[pr2 * PSTR + rs * 5];
        for (int s2 = 0; s2 < NSL; s2++) {
#pragma unroll
            for (int k = 0; k < KNN; k++) {
                float d = dp[s2 * 10 + k];
                unsigned int jj = (unsigned int)(s2 * slen2 + (int)ip[s2 * 10 + k]);
                unsigned long long key = ((unsigned long long)__float_as_uint(d) << 32) | jj;
                if (key < a4u) {                  // exact (d, pos) lex order
                    a4u = key;
                    if (a4u < a3u) { unsigned long long u = a3u; a3u = a4u; a4u = u; }
                    if (a3u < a2u) { unsigned long long u = a2u; a2u = a3u; a3u = u; }
                    if (a2u < a1u) { unsigned long long u = a1u; a1u = a2u; a2u = u; }
                    if (a1u < a0)  { unsigned long long u = a0;  a0  = a1u; a1u = u; }
                }
            }
        }
        if (valid) {
            size_t eb2 = (size_t)b2 * S;
            int irow = qlist[eb2 + r];
            size_t gi = eb2 + irow;
            unsigned long long av[KNN] = {a0, a1u, a2u, a3u, a4u};
            float dk[KNN], nk[KNN], ev[KNN];
            float m = -3.0e38f;
#pragma unroll
            for (int k = 0; k < KNN; k++) {
                float d = __uint_as_float((unsigned int)(av[k] >> 32));
                bool val = (d < BIGF);
                int cpos = (int)(unsigned int)(av[k] & 0xffffffffu);
                if (!val || cpos >= S || cpos < 0) cpos = 0;
                dk[k] = val ? d : 0.0f;
                nk[k] = val ? (float)(b2 * S + clist[eb2 + cpos]) : -1.0f;
                ev[k] = expf(-dk[k]);
                m = fmaxf(m, ev[k]);
            }
            float u[KNN], ssum = 0.0f;
#pragma unroll
            for (int k = 0; k < KNN; k++) { u[k] = expf(ev[k] - m); ssum += u[k]; }
#pragma unroll
            for (int k = 0; k < KNN; k++) {
                out_nidx[gi * KNN + k] = nk[k];
                out_dist[gi * KNN + k] = dk[k];
                out_w[gi * KNN + k]    = u[k] / ssum;
            }
        }
    }
}

extern "C" void kernel_launch(void* const* d_in, const int* in_sizes, int n_in,
                              void* d_out, int out_size, void* d_ws, size_t ws_size,
                              hipStream_t stream) {
    const float* score  = (const float*)d_in[0];
    const float* coords = (const float*)d_in[1];

    float* out = (float*)d_out;
    size_t NK = (size_t)BEV * S * KNN;
    float* out_nidx = out;
    float* out_dist = out + NK;
    float* out_w    = out + 2 * NK;
    float* out_rsup = out + 3 * NK;
    float* out_sel  = out + 3 * NK + (BEV + 1);

    char* ws = (char*)d_ws;
    float* mrss4  = (float*)(ws + 0);                     // 64 f32
    int* qn       = (int*)(ws + 256);                     // 64
    int* cn       = (int*)(ws + 512);                     // 64
    int* qchoff   = (int*)(ws + 768);                     // 64
    int* cchoff   = (int*)(ws + 1024);                    // 64
    int* qcount   = (int*)(ws + 1280);                    // 16
    int* ccount   = (int*)(ws + 1344);                    // 16
    int* qpoff    = (int*)(ws + 1408);                    // 17
    int* scount   = (int*)(ws + 1536);                    // 64
    float* thrv   = (float*)(ws + 1792);                  // 1
    int* qlist    = (int*)(ws + 2048);                    // BEV*S
    int* clist    = (int*)(ws + 2048 + (size_t)BEV * S * 4);
    float4* qpts  = (float4*)(ws + 2048 + (size_t)BEV * S * 8);      // 16B aligned
    float4* ptsc  = (float4*)(ws + 2048 + (size_t)BEV * S * 8 + (size_t)BEV * S * 16);

    k_scan<<<BEV * 4, 1024, 0, stream>>>(score, mrss4, qn, cn);
    k_off<<<1, 64, 0, stream>>>(mrss4, qn, cn, thrv, qchoff, cchoff,
                                qcount, ccount, qpoff);
    k_sel<<<BEV * 4, 1024, 0, stream>>>(score, coords, thrv, qchoff, cchoff, scount,
                                        qlist, clist, qpts, ptsc,
                                        out_nidx, out_dist, out_w, out_sel);
    k_knn<<<(BEV * ((S + 1) / 2) + GPP - 1) / GPP, NTH, 0, stream>>>(
        ptsc, qpts, qlist, clist, qpoff, qcount, ccount, scount,
        out_nidx, out_dist, out_w, out_rsup);
}

// Round 10
// 97.224 us; speedup vs baseline: 2.8114x; 1.0095x over previous
//
#include <hip/hip_runtime.h>
#include <math.h>

#define S      4096
#define BEV    16
#define KNN    5
#define BIGF   1.0e9f
#define NSL    32           // slices per candidate scan
#define GPP    8            // query-pairs per knn block
#define NTH    256          // = GPP * NSL
#define RSTR   81           // per-slice LDS row stride in elements (GPP*10 + 1 pad)

__device__ __forceinline__ float fmulrn(float a, float b) { return __fmul_rn(a, b); }
__device__ __forceinline__ float faddrn(float a, float b) { return __fadd_rn(a, b); }

// ---- K1: per-(event,chunk) stats: chunk max score, query/cand counts (no atomics) ----
__global__ __launch_bounds__(1024) void k_scan(const float* __restrict__ score,
                                               float* __restrict__ mrss4,
                                               int* __restrict__ qn, int* __restrict__ cn) {
    int blk = blockIdx.x, t = threadIdx.x;
    int b = blk >> 2, ch = blk & 3;
    float v = score[(size_t)b * S + ch * 1024 + t];
    float m = v;
    int pk = (v > 0.5f) ? (1 << 16) : 1;
#pragma unroll
    for (int off = 32; off >= 1; off >>= 1) {
        m = fmaxf(m, __shfl_xor(m, off, 64));
        pk += __shfl_xor(pk, off, 64);
    }
    __shared__ float wm[16];
    __shared__ int wp[16];
    int wid = t >> 6;
    if ((t & 63) == 0) { wm[wid] = m; wp[wid] = pk; }
    __syncthreads();
    if (t == 0) {
        float mm = wm[0]; int pp = wp[0];
        for (int w = 1; w < 16; w++) { mm = fmaxf(mm, wm[w]); pp += wp[w]; }
        mrss4[blk] = mm;
        qn[blk] = pp & 0xffff;
        cn[blk] = pp >> 16;
    }
}

// ---- K2: threshold + prefix offsets (single thread; tiny) ----
__global__ void k_off(const float* __restrict__ mrss4,
                      const int* __restrict__ qn, const int* __restrict__ cn,
                      float* __restrict__ thrv,
                      int* __restrict__ qchoff, int* __restrict__ cchoff,
                      int* __restrict__ qcount, int* __restrict__ ccount,
                      int* __restrict__ qpoff) {
    if (threadIdx.x != 0) return;
    float mn = 3.0e38f;
    for (int b = 0; b < BEV; b++) {
        float mx = mrss4[b * 4];
        for (int ch = 1; ch < 4; ch++) mx = fmaxf(mx, mrss4[b * 4 + ch]);
        mn = fminf(mn, mx);
    }
    // rn(0.98*x) monotone => min of products == product of min; clamp 0.5
    thrv[0] = fminf(__fmul_rn(mn, 0.98f), 0.5f);
    int qp = 0;
    for (int b = 0; b < BEV; b++) {
        int qq = 0, cc = 0;
        for (int ch = 0; ch < 4; ch++) {
            qchoff[b * 4 + ch] = qq; cchoff[b * 4 + ch] = cc;
            qq += qn[b * 4 + ch];    cc += cn[b * 4 + ch];
        }
        qcount[b] = qq; ccount[b] = cc;
        qpoff[b] = qp; qp += (qq + 1) >> 1;      // pairs of query rows
    }
    qpoff[BEV] = qp;
}

// ---- K3: ordered compaction + sel_mask + candidate defaults + sel counts ----
__global__ __launch_bounds__(1024) void k_sel(const float* __restrict__ score,
                                              const float* __restrict__ coords,
                                              const float* __restrict__ thrv,
                                              const int* __restrict__ qchoff,
                                              const int* __restrict__ cchoff,
                                              int* __restrict__ scount,
                                              int* __restrict__ qlist,
                                              int* __restrict__ clist,
                                              float4* __restrict__ qpts,
                                              float4* __restrict__ ptsc,
                                              float* __restrict__ out_nidx,
                                              float* __restrict__ out_dist,
                                              float* __restrict__ out_w,
                                              float* __restrict__ out_sel) {
    int blk = blockIdx.x, t = threadIdx.x;
    int b = blk >> 2, ch = blk & 3;
    int p = ch * 1024 + t;
    size_t gi = (size_t)b * S + p;
    float v = score[gi];
    float thr = thrv[0];
    out_sel[gi] = (v >= thr) ? 1.0f : 0.0f;
    bool cand = (v > 0.5f);
    int pk = cand ? (1 << 16) : 1;
    int incl = pk;
#pragma unroll
    for (int off = 1; off < 64; off <<= 1) {
        int u = __shfl_up(incl, off, 64);
        if ((t & 63) >= off) incl += u;
    }
    __shared__ int wtot[16];
    __shared__ int wsel[16];
    int wid = t >> 6;
    if ((t & 63) == 63) wtot[wid] = incl;
    int sel = (v >= thr) ? 1 : 0;
#pragma unroll
    for (int off = 32; off >= 1; off >>= 1) sel += __shfl_xor(sel, off, 64);
    if ((t & 63) == 0) wsel[wid] = sel;
    __syncthreads();
    int base = 0;
    for (int w = 0; w < wid; w++) base += wtot[w];
    int excl = base + incl - pk;
    if (t == 0) {
        int sc2 = 0;
        for (int w = 0; w < 16; w++) sc2 += wsel[w];
        scount[blk] = sc2;
    }
    const float* c = coords + gi * 3;
    float x = c[0], y = c[1], z = c[2];
    float xx = faddrn(faddrn(fmulrn(x, x), fmulrn(y, y)), fmulrn(z, z));
    size_t ebase = (size_t)b * S;
    if (cand) {
        int pos = cchoff[blk] + (excl >> 16);
        clist[ebase + pos] = p;
        ptsc[ebase + pos] = make_float4(fmulrn(-2.0f, x), fmulrn(-2.0f, y),
                                        fmulrn(-2.0f, z), xx);
        // direction-0 rows: fixed default outputs
#pragma unroll
        for (int k = 0; k < KNN; k++) {
            out_nidx[gi * KNN + k] = -1.0f;
            out_dist[gi * KNN + k] = 0.0f;
            out_w[gi * KNN + k]    = 0.2f;
        }
    } else {
        int pos = qchoff[blk] + (excl & 0xffff);
        qlist[ebase + pos] = p;
        qpts[ebase + pos] = make_float4(x, y, z, xx);
    }
}

// ---- K4: fused KNN: 2 rows/thread x 32 slices, med3 insert, LDS merge + epilogue ----
__global__ __launch_bounds__(NTH, 4) void k_knn(const float4* __restrict__ ptsc,
                                                const float4* __restrict__ qpts,
                                                const int* __restrict__ qlist,
                                                const int* __restrict__ clist,
                                                const int* __restrict__ qpoff,
                                                const int* __restrict__ qcount,
                                                const int* __restrict__ ccount,
                                                const int* __restrict__ scount,
                                                float* __restrict__ out_nidx,
                                                float* __restrict__ out_dist,
                                                float* __restrict__ out_w,
                                                float* __restrict__ out_rsup) {
    int pg = blockIdx.x, t = threadIdx.x;
    if (pg == 0 && t == 0) {                     // rs_up prefix (17 floats)
        int acc = 0;
        out_rsup[0] = 0.0f;
        for (int e = 0; e < BEV; e++) {
            acc += scount[e * 4] + scount[e * 4 + 1] + scount[e * 4 + 2] + scount[e * 4 + 3];
            out_rsup[e + 1] = (float)acc;
        }
    }
    int total = qpoff[BEV];
    if (pg * GPP >= total) return;               // uniform exit

    __shared__ int sqp[BEV + 1];
    __shared__ int sqc[BEV];
    __shared__ int scc[BEV];
    __shared__ float dpart[NSL * RSTR];          // [sl][pr*10], 10368 B
    __shared__ unsigned short ipart[NSL * RSTR]; // 5184 B
    if (t < BEV + 1) sqp[t] = qpoff[t];
    if (t < BEV) { sqc[t] = qcount[t]; scc[t] = ccount[t]; }
    __syncthreads();

    int pr = t & (GPP - 1), sl = t >> 3;         // 8 pairs x 32 slices
    int gpr = pg * GPP + pr;
    bool pact = gpr < total;
    int gp = pact ? gpr : (total - 1);
    int b = 0;
#pragma unroll
    for (int e = 1; e < BEV; e++) b += (gp >= sqp[e]) ? 1 : 0;
    int rp = gp - sqp[b];
    int qc = sqc[b], cc = scc[b];
    int r0 = 2 * rp, r1 = r0 + 1;
    bool a1v = pact && (r1 < qc);
    size_t ebase = (size_t)b * S;
    float4 q0 = qpts[ebase + r0];
    float4 q1 = qpts[ebase + (a1v ? r1 : r0)];

    int slen = (cc + NSL - 1) / NSL;
    int j0 = sl * slen;
    int j1 = min(j0 + slen, cc);

    const float INF = __int_as_float(0x7f800000);
    float A0=INF,A1=INF,A2=INF,A3=INF,A4=INF; int IA0=-1,IA1=-1,IA2=-1,IA3=-1,IA4=-1;
    float B0=INF,B1=INF,B2=INF,B3=INF,B4=INF; int IB0=-1,IB1=-1,IB2=-1,IB3=-1,IB4=-1;
    const float4* __restrict__ pp = ptsc + ebase;

#pragma unroll 4
    for (int j = j0; j < j1; j++) {
        float4 p = pp[j];                        // 8 distinct addrs per wave
        float dm0 = faddrn(faddrn(fmulrn(p.x, q0.x), fmulrn(p.y, q0.y)), fmulrn(p.z, q0.z));
        float dd0 = fmaxf(faddrn(faddrn(q0.w, p.w), dm0), 0.0f);
        float dm1 = faddrn(faddrn(fmulrn(p.x, q1.x), fmulrn(p.y, q1.y)), fmulrn(p.z, q1.z));
        float dd1 = fmaxf(faddrn(faddrn(q1.w, p.w), dm1), 0.0f);
        {   // sorted insert: compares (old values) drive idx; med3 updates values
            bool c0=dd0<A0,c1=dd0<A1,c2=dd0<A2,c3=dd0<A3,c4=dd0<A4;
            IA4=c4?(c3?IA3:j):IA4; IA3=c3?(c2?IA2:j):IA3; IA2=c2?(c1?IA1:j):IA2;
            IA1=c1?(c0?IA0:j):IA1; IA0=c0?j:IA0;
            A4=__builtin_amdgcn_fmed3f(dd0,A3,A4); A3=__builtin_amdgcn_fmed3f(dd0,A2,A3);
            A2=__builtin_amdgcn_fmed3f(dd0,A1,A2); A1=__builtin_amdgcn_fmed3f(dd0,A0,A1);
            A0=fminf(A0,dd0);
        }
        {
            bool c0=dd1<B0,c1=dd1<B1,c2=dd1<B2,c3=dd1<B3,c4=dd1<B4;
            IB4=c4?(c3?IB3:j):IB4; IB3=c3?(c2?IB2:j):IB3; IB2=c2?(c1?IB1:j):IB2;
            IB1=c1?(c0?IB0:j):IB1; IB0=c0?j:IB0;
            B4=__builtin_amdgcn_fmed3f(dd1,B3,B4); B3=__builtin_amdgcn_fmed3f(dd1,B2,B3);
            B2=__builtin_amdgcn_fmed3f(dd1,B1,B2); B1=__builtin_amdgcn_fmed3f(dd1,B0,B1);
            B0=fminf(B0,dd1);
        }
    }

    float* wd = &dpart[sl * RSTR + pr * 10];
    unsigned short* wi = &ipart[sl * RSTR + pr * 10];
    wd[0]=A0; wd[1]=A1; wd[2]=A2; wd[3]=A3; wd[4]=A4;
    wd[5]=B0; wd[6]=B1; wd[7]=B2; wd[8]=B3; wd[9]=B4;
    wi[0]=(unsigned short)(IA0-j0); wi[1]=(unsigned short)(IA1-j0);
    wi[2]=(unsigned short)(IA2-j0); wi[3]=(unsigned short)(IA3-j0);
    wi[4]=(unsigned short)(IA4-j0);
    wi[5]=(unsigned short)(IB0-j0); wi[6]=(unsigned short)(IB1-j0);
    wi[7]=(unsigned short)(IB2-j0); wi[8]=(unsigned short)(IB3-j0);
    wi[9]=(unsigned short)(IB4-j0);
    __syncthreads();

    if (t < 2 * GPP) {                           // 16 merge threads
        int pr2 = t >> 1, rs = t & 1;
        int gpr2 = pg * GPP + pr2;
        bool pact2 = gpr2 < total;
        int gp2 = pact2 ? gpr2 : (total - 1);
        int b2 = 0;
#pragma unroll
        for (int e = 1; e < BEV; e++) b2 += (gp2 >= sqp[e]) ? 1 : 0;
        int rp2 = gp2 - sqp[b2];
        int qc2 = sqc[b2], cc2 = scc[b2];
        int slen2 = (cc2 + NSL - 1) / NSL;
        int r = 2 * rp2 + rs;
        bool valid = pact2 && (r < qc2);

        unsigned long long a0=~0ull, a1u=~0ull, a2u=~0ull, a3u=~0ull, a4u=~0ull;
        for (int s2 = 0; s2 < NSL; s2++) {
            const float* dp = &dpart[s2 * RSTR + pr2 * 10 + rs * 5];
            const unsigned short* ip = &ipart[s2 * RSTR + pr2 * 10 + rs * 5];
#pragma unroll
            for (int k = 0; k < KNN; k++) {
                float d = dp[k];
                unsigned int jj = (unsigned int)(s2 * slen2 + (int)ip[k]);
                unsigned long long key = ((unsigned long long)__float_as_uint(d) << 32) | jj;
                if (key < a4u) {                  // exact (d, pos) lex order
                    a4u = key;
                    if (a4u < a3u) { unsigned long long u = a3u; a3u = a4u; a4u = u; }
                    if (a3u < a2u) { unsigned long long u = a2u; a2u = a3u; a3u = u; }
                    if (a2u < a1u) { unsigned long long u = a1u; a1u = a2u; a2u = u; }
                    if (a1u < a0)  { unsigned long long u = a0;  a0  = a1u; a1u = u; }
                }
            }
        }
        if (valid) {
            size_t eb2 = (size_t)b2 * S;
            int irow = qlist[eb2 + r];
            size_t gi = eb2 + irow;
            unsigned long long av[KNN] = {a0, a1u, a2u, a3u, a4u};
            float dk[KNN], nk[KNN], ev[KNN];
            float m = -3.0e38f;
#pragma unroll
            for (int k = 0; k < KNN; k++) {
                float d = __uint_as_float((unsigned int)(av[k] >> 32));
                bool val = (d < BIGF);
                int cpos = (int)(unsigned int)(av[k] & 0xffffffffu);
                if (!val || cpos >= S || cpos < 0) cpos = 0;
                dk[k] = val ? d : 0.0f;
                nk[k] = val ? (float)(b2 * S + clist[eb2 + cpos]) : -1.0f;
                ev[k] = expf(-dk[k]);
                m = fmaxf(m, ev[k]);
            }
            float u[KNN], ssum = 0.0f;
#pragma unroll
            for (int k = 0; k < KNN; k++) { u[k] = expf(ev[k] - m); ssum += u[k]; }
#pragma unroll
            for (int k = 0; k < KNN; k++) {
                out_nidx[gi * KNN + k] = nk[k];
                out_dist[gi * KNN + k] = dk[k];
                out_w[gi * KNN + k]    = u[k] / ssum;
            }
        }
    }
}

extern "C" void kernel_launch(void* const* d_in, const int* in_sizes, int n_in,
                              void* d_out, int out_size, void* d_ws, size_t ws_size,
                              hipStream_t stream) {
    const float* score  = (const float*)d_in[0];
    const float* coords = (const float*)d_in[1];

    float* out = (float*)d_out;
    size_t NK = (size_t)BEV * S * KNN;
    float* out_nidx = out;
    float* out_dist = out + NK;
    float* out_w    = out + 2 * NK;
    float* out_rsup = out + 3 * NK;
    float* out_sel  = out + 3 * NK + (BEV + 1);

    char* ws = (char*)d_ws;
    float* mrss4  = (float*)(ws + 0);                     // 64 f32
    int* qn       = (int*)(ws + 256);                     // 64
    int* cn       = (int*)(ws + 512);                     // 64
    int* qchoff   = (int*)(ws + 768);                     // 64
    int* cchoff   = (int*)(ws + 1024);                    // 64
    int* qcount   = (int*)(ws + 1280);                    // 16
    int* ccount   = (int*)(ws + 1344);                    // 16
    int* qpoff    = (int*)(ws + 1408);                    // 17
    int* scount   = (int*)(ws + 1536);                    // 64
    float* thrv   = (float*)(ws + 1792);                  // 1
    int* qlist    = (int*)(ws + 2048);                    // BEV*S
    int* clist    = (int*)(ws + 2048 + (size_t)BEV * S * 4);
    float4* qpts  = (float4*)(ws + 2048 + (size_t)BEV * S * 8);      // 16B aligned
    float4* ptsc  = (float4*)(ws + 2048 + (size_t)BEV * S * 8 + (size_t)BEV * S * 16);

    k_scan<<<BEV * 4, 1024, 0, stream>>>(score, mrss4, qn, cn);
    k_off<<<1, 64, 0, stream>>>(mrss4, qn, cn, thrv, qchoff, cchoff,
                                qcount, ccount, qpoff);
    k_sel<<<BEV * 4, 1024, 0, stream>>>(score, coords, thrv, qchoff, cchoff, scount,
                                        qlist, clist, qpts, ptsc,
                                        out_nidx, out_dist, out_w, out_sel);
    k_knn<<<(BEV * ((S + 1) / 2) + GPP - 1) / GPP, NTH, 0, stream>>>(
        ptsc, qpts, qlist, clist, qpoff, qcount, ccount, scount,
        out_nidx, out_dist, out_w, out_rsup);
}